// Round 7
// baseline (510.461 us; speedup 1.0000x reference)
//
#include <hip/hip_runtime.h>

#define EPSF 1e-5f

__device__ __forceinline__ float elu_f(float x) { return x > 0.f ? x : expm1f(x); }

// ---------------- CSR build ----------------

__global__ __launch_bounds__(256) void k_zero(int* p, int n) {
    int i = blockIdx.x * 256 + threadIdx.x;
    if (i < n) p[i] = 0;
}

// XCD-range-partitioned count, nt loads: group g = blockIdx&7 owns dst range [g*N8, ...).
// nt load on the dst stream avoids evicting the (tiny, XCD-local) dirty cnt lines from L2.
__global__ __launch_bounds__(256) void k_count_x(const int* __restrict__ dst, int* __restrict__ cnt,
                                                 int E, int N) {
    int g = blockIdx.x & 7;
    int cb = blockIdx.x >> 3;
    int nch = gridDim.x >> 3;
    int N8 = (N + 7) >> 3;
    int lo = g * N8;
    int hi = min(N, lo + N8);
    for (long e = (long)cb * 256 + threadIdx.x; e < E; e += (long)nch * 256) {
        int d = __builtin_nontemporal_load(&dst[e]);
        if (d >= lo && d < hi) atomicAdd(&cnt[d], 1);
    }
}

#define SCAN_T 256
#define SCAN_E 4
#define SCAN_B (SCAN_T * SCAN_E)  // 1024 elems per block

// scan over cnt -> base (block-local), block sums -> bsum; also dinv = rsqrt(cnt+1)
__global__ __launch_bounds__(256) void k_scan1(const int* __restrict__ cnt, int* __restrict__ base,
                                               int* __restrict__ bsum, float* __restrict__ dinv, int n) {
    __shared__ int sh[SCAN_T];
    int t = threadIdx.x;
    int b0 = blockIdx.x * SCAN_B;
    int v[SCAN_E];
    int tsum = 0;
    #pragma unroll
    for (int j = 0; j < SCAN_E; ++j) {
        int idx = b0 + t * SCAN_E + j;
        v[j] = (idx < n) ? cnt[idx] : 0;
        if (idx < n) dinv[idx] = rsqrtf((float)(v[j] + 1));  // +1 self-loop
        tsum += v[j];
    }
    sh[t] = tsum;
    __syncthreads();
    for (int off = 1; off < SCAN_T; off <<= 1) {
        int add = (t >= off) ? sh[t - off] : 0;
        __syncthreads();
        sh[t] += add;
        __syncthreads();
    }
    int run = sh[t] - tsum;  // exclusive prefix of this thread
    if (t == SCAN_T - 1) bsum[blockIdx.x] = sh[t];
    #pragma unroll
    for (int j = 0; j < SCAN_E; ++j) {
        int idx = b0 + t * SCAN_E + j;
        if (idx < n) base[idx] = run;
        run += v[j];
    }
}

__global__ __launch_bounds__(256) void k_scan2(int* bsum, int nb) {
    __shared__ int sh[SCAN_T];
    int t = threadIdx.x;
    int v = (t < nb) ? bsum[t] : 0;
    sh[t] = v;
    __syncthreads();
    for (int off = 1; off < SCAN_T; off <<= 1) {
        int add = (t >= off) ? sh[t - off] : 0;
        __syncthreads();
        sh[t] += add;
        __syncthreads();
    }
    if (t < nb) bsum[t] = sh[t] - v;  // exclusive
}

// finalize base and seed fcnt = base (fill then uses atomicAdd(&fcnt[d],1) directly)
__global__ __launch_bounds__(256) void k_scan3(int* base, int* fcnt, const int* __restrict__ bsum, int n) {
    int i = blockIdx.x * 256 + threadIdx.x;
    if (i < n) {
        int v = base[i] + bsum[i / SCAN_B];
        base[i] = v;
        fcnt[i] = v;
    }
}

// XCD-range-partitioned packed fill, nt loads on edge streams: scattered 8B csr writes
// use regular (cached) stores so the XCD-local 1.6MB dirty region merges in L2 and
// writes back once; nt loads keep the 58MB read stream from evicting those lines.
__global__ __launch_bounds__(256) void k_fill_x(const int* __restrict__ src, const int* __restrict__ dst,
                                                int* __restrict__ fcnt, const float* __restrict__ dinv,
                                                int2* __restrict__ csr_sw, int E, int N) {
    int g = blockIdx.x & 7;
    int cb = blockIdx.x >> 3;
    int nch = gridDim.x >> 3;
    int N8 = (N + 7) >> 3;
    int lo = g * N8;
    int hi = min(N, lo + N8);
    for (long e = (long)cb * 256 + threadIdx.x; e < E; e += (long)nch * 256) {
        int d = __builtin_nontemporal_load(&dst[e]);
        if (d >= lo && d < hi) {
            int s = __builtin_nontemporal_load(&src[e]);
            int pos = atomicAdd(&fcnt[d], 1);
            int2 sw;
            sw.x = s;
            sw.y = __float_as_int(dinv[s]);  // dinv[dst] hoisted into gather epilogue
            csr_sw[pos] = sw;
        }
    }
}

// ---------------- CSR gather-aggregate ----------------
// out[i] = dinv_i * ( sum_e w_e * x[src_e] + dinv_i * x[i] )  [+ bias/BN/ELU epilogue]
template<int F, bool L1EPI>
__global__ __launch_bounds__(256) void k_gather(const int* __restrict__ base, const int* __restrict__ cnt,
                                                const int2* __restrict__ csr_sw,
                                                const float* __restrict__ dinv, const float* __restrict__ xin,
                                                const float* __restrict__ b, const float* __restrict__ g,
                                                const float* __restrict__ be, const float* __restrict__ rm,
                                                const float* __restrict__ rv, float* __restrict__ out, int n) {
    constexpr int C = F / 4;          // float4 lanes per node
    constexpr int NPB = 256 / C;      // nodes per block
    int lane = threadIdx.x % C;
    int nl = threadIdx.x / C;
    int i = blockIdx.x * NPB + nl;
    if (i >= n) return;
    int k = base[i];
    int kend = k + cnt[i];
    float di = dinv[i];
    const float4* X4 = reinterpret_cast<const float4*>(xin);
    float4 acc = {0.f, 0.f, 0.f, 0.f};
    float4 acc2 = {0.f, 0.f, 0.f, 0.f};
    for (; k + 1 < kend; k += 2) {
        int2 ea = csr_sw[k];
        int2 eb = csr_sw[k + 1];
        float wa = __int_as_float(ea.y);
        float wb = __int_as_float(eb.y);
        float4 xa = X4[(long)ea.x * C + lane];
        float4 xb = X4[(long)eb.x * C + lane];
        acc.x += wa * xa.x; acc.y += wa * xa.y; acc.z += wa * xa.z; acc.w += wa * xa.w;
        acc2.x += wb * xb.x; acc2.y += wb * xb.y; acc2.z += wb * xb.z; acc2.w += wb * xb.w;
    }
    if (k < kend) {
        int2 ea = csr_sw[k];
        float wa = __int_as_float(ea.y);
        float4 xa = X4[(long)ea.x * C + lane];
        acc.x += wa * xa.x; acc.y += wa * xa.y; acc.z += wa * xa.z; acc.w += wa * xa.w;
    }
    acc.x += acc2.x; acc.y += acc2.y; acc.z += acc2.z; acc.w += acc2.w;
    float4 xs = X4[(long)i * C + lane];
    float4 o;
    o.x = di * (acc.x + di * xs.x);
    o.y = di * (acc.y + di * xs.y);
    o.z = di * (acc.z + di * xs.z);
    o.w = di * (acc.w + di * xs.w);
    if (L1EPI) {
        float4 bb = reinterpret_cast<const float4*>(b)[lane];
        float4 gg = reinterpret_cast<const float4*>(g)[lane];
        float4 ee = reinterpret_cast<const float4*>(be)[lane];
        float4 mm = reinterpret_cast<const float4*>(rm)[lane];
        float4 vv = reinterpret_cast<const float4*>(rv)[lane];
        o.x = elu_f((o.x + bb.x - mm.x) * rsqrtf(vv.x + EPSF) * gg.x + ee.x);
        o.y = elu_f((o.y + bb.y - mm.y) * rsqrtf(vv.y + EPSF) * gg.y + ee.y);
        o.z = elu_f((o.z + bb.z - mm.z) * rsqrtf(vv.z + EPSF) * gg.z + ee.z);
        o.w = elu_f((o.w + bb.w - mm.w) * rsqrtf(vv.w + EPSF) * gg.w + ee.w);
    }
    reinterpret_cast<float4*>(out)[(long)i * C + lane] = o;
}

// scalar gather for layer 4 + final sigmoid(elu(.)) epilogue, writes d_out
__global__ __launch_bounds__(256) void k_gather1_final(const int* __restrict__ base, const int* __restrict__ cnt,
                                                       const int2* __restrict__ csr_sw,
                                                       const float* __restrict__ dinv, const float* __restrict__ y,
                                                       const float* __restrict__ b4, float* __restrict__ out, int n) {
    int i = blockIdx.x * 256 + threadIdx.x;
    if (i >= n) return;
    int k = base[i];
    int kend = k + cnt[i];
    float di = dinv[i];
    float acc = 0.f;
    for (; k < kend; ++k) {
        int2 ea = csr_sw[k];
        acc += __int_as_float(ea.y) * y[ea.x];
    }
    float v = di * (acc + di * y[i]) + b4[0];
    v = elu_f(v);
    out[i] = 1.f / (1.f + expf(-v));
}

// ---------------- register-tiled dense GEMM ----------------
// Thread: TR=4 rows x 4 fouts. W staged in LDS, one ds_read_b128 per k shared by 4 rows.
// __launch_bounds__(256,4): cap VGPR at 128 so >=4 waves/SIMD (R3 lesson).
// #pragma unroll 2 keeps only 2 k0-iterations of X loads in flight.
template<int DIN, int DOUT, bool BN, bool FUSE_DOT>
__global__ __launch_bounds__(256, 4) void k_gemm_rt(const float* __restrict__ X, const float* __restrict__ W,
                                                    const float* __restrict__ b, const float* __restrict__ g,
                                                    const float* __restrict__ be, const float* __restrict__ rm,
                                                    const float* __restrict__ rv, const float* __restrict__ W4,
                                                    float* __restrict__ Y, int n) {
    constexpr int TR = 4;
    constexpr int FL = DOUT / 4;       // fout-lane groups
    constexpr int RG = 256 / FL;       // row-groups per block
    constexpr int BR = RG * TR;        // rows per block
    __shared__ float Wl[DIN * DOUT];
    for (int idx = threadIdx.x; idx < DIN * DOUT; idx += 256) Wl[idx] = W[idx];
    __syncthreads();
    const int fl = threadIdx.x % FL;
    const int rg = threadIdx.x / FL;
    const int f0 = fl * 4;
    const long r0 = (long)blockIdx.x * BR + (long)rg * TR;

    float4 z; z.x = z.y = z.z = z.w = 0.f;
    float4 acc[TR];
    #pragma unroll
    for (int r = 0; r < TR; ++r) acc[r] = z;

    #pragma unroll 2
    for (int k0 = 0; k0 < DIN; k0 += 4) {
        float4 xv[TR];
        #pragma unroll
        for (int r = 0; r < TR; ++r) {
            long row = r0 + r;
            xv[r] = (row < n) ? *reinterpret_cast<const float4*>(X + row * DIN + k0) : z;
        }
        #pragma unroll
        for (int kk = 0; kk < 4; ++kk) {
            float4 w4 = *reinterpret_cast<const float4*>(&Wl[(k0 + kk) * DOUT + f0]);
            #pragma unroll
            for (int r = 0; r < TR; ++r) {
                float xs = (kk == 0) ? xv[r].x : (kk == 1) ? xv[r].y : (kk == 2) ? xv[r].z : xv[r].w;
                acc[r].x += xs * w4.x;
                acc[r].y += xs * w4.y;
                acc[r].z += xs * w4.z;
                acc[r].w += xs * w4.w;
            }
        }
    }

    float4 bias = z, scale = z, shift = z, w4d = z;
    if (BN) {
        bias = *reinterpret_cast<const float4*>(b + f0);
        float4 gg = *reinterpret_cast<const float4*>(g + f0);
        float4 ee = *reinterpret_cast<const float4*>(be + f0);
        float4 mm = *reinterpret_cast<const float4*>(rm + f0);
        float4 vv = *reinterpret_cast<const float4*>(rv + f0);
        scale.x = gg.x * rsqrtf(vv.x + EPSF); shift.x = ee.x - mm.x * scale.x;
        scale.y = gg.y * rsqrtf(vv.y + EPSF); shift.y = ee.y - mm.y * scale.y;
        scale.z = gg.z * rsqrtf(vv.z + EPSF); shift.z = ee.z - mm.z * scale.z;
        scale.w = gg.w * rsqrtf(vv.w + EPSF); shift.w = ee.w - mm.w * scale.w;
    }
    if (FUSE_DOT) w4d = *reinterpret_cast<const float4*>(W4 + f0);

    #pragma unroll
    for (int r = 0; r < TR; ++r) {
        long row = r0 + r;
        if (row >= n) continue;
        float4 v = acc[r];
        if (BN) {
            v.x = elu_f((v.x + bias.x) * scale.x + shift.x);
            v.y = elu_f((v.y + bias.y) * scale.y + shift.y);
            v.z = elu_f((v.z + bias.z) * scale.z + shift.z);
            v.w = elu_f((v.w + bias.w) * scale.w + shift.w);
        }
        if (FUSE_DOT) {
            float p = v.x * w4d.x + v.y * w4d.y + v.z * w4d.z + v.w * w4d.w;
            #pragma unroll
            for (int m = 1; m < FL; m <<= 1) p += __shfl_xor(p, m, 64);
            if (fl == 0) Y[row] = p;
        } else {
            *reinterpret_cast<float4*>(Y + row * DOUT + f0) = v;
        }
    }
}

// ---------------- launch ----------------

extern "C" void kernel_launch(void* const* d_in, const int* in_sizes, int n_in,
                              void* d_out, int out_size, void* d_ws, size_t ws_size,
                              hipStream_t stream) {
    const float* x   = (const float*)d_in[0];
    const int*   edg = (const int*)d_in[1];
    const float* W1 = (const float*)d_in[2];
    const float* b1 = (const float*)d_in[3];
    const float* W2 = (const float*)d_in[4];
    const float* b2 = (const float*)d_in[5];
    const float* W3 = (const float*)d_in[6];
    const float* b3 = (const float*)d_in[7];
    const float* W4 = (const float*)d_in[8];
    const float* b4 = (const float*)d_in[9];
    const float* g1  = (const float*)d_in[10];
    const float* be1 = (const float*)d_in[11];
    const float* rm1 = (const float*)d_in[12];
    const float* rv1 = (const float*)d_in[13];
    const float* g2  = (const float*)d_in[14];
    const float* be2 = (const float*)d_in[15];
    const float* rm2 = (const float*)d_in[16];
    const float* rv2 = (const float*)d_in[17];
    const float* g3  = (const float*)d_in[18];
    const float* be3 = (const float*)d_in[19];
    const float* rm3 = (const float*)d_in[20];
    const float* rv3 = (const float*)d_in[21];
    float* out = (float*)d_out;

    const int N = in_sizes[0] / 64;
    const int E = in_sizes[1] / 2;
    const int* src = edg;
    const int* dst = edg + E;
    const int NB_SCAN = (N + SCAN_B - 1) / SCAN_B;

    // workspace layout (all 16B-aligned by construction)
    int*   cnt     = (int*)d_ws;                    // N
    int*   fcnt    = cnt + N;                       // N
    int*   base    = fcnt + N;                      // N
    int*   bsum    = base + N;                      // 256
    int2*  csr_sw  = (int2*)(bsum + 256);           // E int2 (8B-aligned)
    float* dinv    = (float*)(csr_sw + E);          // N
    float* A       = dinv + N;                      // N*64 max
    float* B       = A + (size_t)N * 64;            // N*128 max... (N*64 used)

    auto nb = [](long total) { return (int)((total + 255) / 256); };

    // CSR build (per call: workspace re-poisoned every launch)
    k_zero<<<nb(N), 256, 0, stream>>>(cnt, N);
    k_count_x<<<2048, 256, 0, stream>>>(dst, cnt, E, N);
    k_scan1<<<NB_SCAN, 256, 0, stream>>>(cnt, base, bsum, dinv, N);
    k_scan2<<<1, 256, 0, stream>>>(bsum, NB_SCAN);
    k_scan3<<<nb(N), 256, 0, stream>>>(base, fcnt, bsum, N);
    k_fill_x<<<2048, 256, 0, stream>>>(src, dst, fcnt, dinv, csr_sw, E, N);

    // Layer 1 (64->32): GEMM, then gather-agg fused with bias+BN+ELU
    k_gemm_rt<64, 32, false, false><<<(N + 127) / 128, 256, 0, stream>>>(
        x, W1, nullptr, nullptr, nullptr, nullptr, nullptr, nullptr, A, N);
    k_gather<32, true><<<(N + 31) / 32, 256, 0, stream>>>(base, cnt, csr_sw, dinv, A,
                                                          b1, g1, be1, rm1, rv1, B, N);

    // Layer 2 (32->64): gather-agg first, then fused GEMM+bias+BN+ELU
    k_gather<32, false><<<(N + 31) / 32, 256, 0, stream>>>(base, cnt, csr_sw, dinv, B,
                                                           nullptr, nullptr, nullptr, nullptr, nullptr, A, N);
    k_gemm_rt<32, 64, true, false><<<(N + 63) / 64, 256, 0, stream>>>(
        A, W2, b2, g2, be2, rm2, rv2, nullptr, B, N);

    // Layer 3 (64->128): gather-agg, then fused GEMM+bias+BN+ELU+dot(W4) -> y in B
    k_gather<64, false><<<(N + 15) / 16, 256, 0, stream>>>(base, cnt, csr_sw, dinv, B,
                                                           nullptr, nullptr, nullptr, nullptr, nullptr, A, N);
    k_gemm_rt<64, 128, true, true><<<(N + 31) / 32, 256, 0, stream>>>(
        A, W3, b3, g3, be3, rm3, rv3, W4, B, N);

    // Layer 4 (128->1): scalar gather-agg fused with bias + sigmoid(elu(.)) -> d_out
    k_gather1_final<<<nb(N), 256, 0, stream>>>(base, cnt, csr_sw, dinv, B, b4, out, N);
}

// Round 8
// 422.424 us; speedup vs baseline: 1.2084x; 1.2084x over previous
//
#include <hip/hip_runtime.h>

#define EPSF 1e-5f
#define BKT_SHIFT 9
#define BKT_NODES 512              // nodes per bucket
#define TILE_E 4096                // edges per k_bpart block

__device__ __forceinline__ float elu_f(float x) { return x > 0.f ? x : expm1f(x); }

// ---------------- bucketed CSR build ----------------

__global__ __launch_bounds__(256) void k_zero(int* p, int n) {
    int i = blockIdx.x * 256 + threadIdx.x;
    if (i < n) p[i] = 0;
}

// coarse bucket histogram (bucket = dst>>9), LDS-staged
__global__ __launch_bounds__(256) void k_bhist(const int* __restrict__ dst, int* __restrict__ bkt_cnt, int E) {
    __shared__ int h[256];
    int t = threadIdx.x;
    h[t] = 0;
    __syncthreads();
    for (long e = (long)blockIdx.x * 256 + t; e < E; e += (long)gridDim.x * 256)
        atomicAdd(&h[dst[e] >> BKT_SHIFT], 1);
    __syncthreads();
    if (h[t]) atomicAdd(&bkt_cnt[t], h[t]);
}

// exclusive scan of 256 bucket counts -> bbase; cursor = bbase copy
__global__ __launch_bounds__(256) void k_bscan(const int* __restrict__ bkt_cnt, int* __restrict__ bbase,
                                               int* __restrict__ cursor) {
    __shared__ int sh[256];
    int t = threadIdx.x;
    int v = bkt_cnt[t];
    sh[t] = v;
    __syncthreads();
    for (int off = 1; off < 256; off <<= 1) {
        int add = (t >= off) ? sh[t - off] : 0;
        __syncthreads();
        sh[t] += add;
        __syncthreads();
    }
    int ex = sh[t] - v;
    bbase[t] = ex;
    cursor[t] = ex;
}

// partition edges into bucket-contiguous csr_tmp = {dst, src}.
// Per 4096-edge tile: LDS rank within (tile,bucket), one global atomicAdd per bucket,
// then writes land in ~21-entry contiguous runs (~full cache lines).
__global__ __launch_bounds__(256) void k_bpart(const int* __restrict__ src, const int* __restrict__ dst,
                                               int* __restrict__ cursor, int2* __restrict__ csr_tmp, int E) {
    __shared__ int hcnt[256];
    __shared__ int gbase[256];
    int t = threadIdx.x;
    long tile0 = (long)blockIdx.x * TILE_E;
    hcnt[t] = 0;
    __syncthreads();
    int d[16], s[16], rk[16];
    #pragma unroll
    for (int j = 0; j < 16; ++j) {
        long e = tile0 + j * 256 + t;
        if (e < E) {
            d[j] = dst[e];
            s[j] = src[e];
            rk[j] = atomicAdd(&hcnt[d[j] >> BKT_SHIFT], 1);
        }
    }
    __syncthreads();
    int c = hcnt[t];
    if (c) gbase[t] = atomicAdd(&cursor[t], c);
    __syncthreads();
    #pragma unroll
    for (int j = 0; j < 16; ++j) {
        long e = tile0 + j * 256 + t;
        if (e < E) {
            int2 q;
            q.x = d[j];
            q.y = s[j];
            csr_tmp[gbase[d[j] >> BKT_SHIFT] + rk[j]] = q;
        }
    }
}

// per-bucket fine CSR: 512-node LDS histogram + scan -> cnt/base/dinv (coalesced),
// then scatter src into the bucket's own (L2-hot, ~32KB) csr_s window.
__global__ __launch_bounds__(256) void k_bfine(const int2* __restrict__ csr_tmp, const int* __restrict__ bbase,
                                               const int* __restrict__ bkt_cnt, int* __restrict__ cnt,
                                               int* __restrict__ base, float* __restrict__ dinv,
                                               int* __restrict__ csr_s, int N) {
    __shared__ int cnt5[BKT_NODES];
    __shared__ int off5[BKT_NODES];
    __shared__ int sh[256];
    int b = blockIdx.x;
    int t = threadIdx.x;
    int d0 = b << BKT_SHIFT;
    int bb = bbase[b];
    int bc = bkt_cnt[b];
    cnt5[t] = 0;
    cnt5[t + 256] = 0;
    __syncthreads();
    for (int k = t; k < bc; k += 256) atomicAdd(&cnt5[csr_tmp[bb + k].x - d0], 1);
    __syncthreads();
    int v0 = cnt5[2 * t], v1 = cnt5[2 * t + 1];
    int p = v0 + v1;
    sh[t] = p;
    __syncthreads();
    for (int off = 1; off < 256; off <<= 1) {
        int add = (t >= off) ? sh[t - off] : 0;
        __syncthreads();
        sh[t] += add;
        __syncthreads();
    }
    int pre = sh[t] - p;
    off5[2 * t] = pre;
    off5[2 * t + 1] = pre + v0;
    #pragma unroll
    for (int j = 0; j < 2; ++j) {
        int idx = 2 * t + j;
        int i = d0 + idx;
        if (i < N) {
            int c = cnt5[idx];
            base[i] = bb + off5[idx];
            cnt[i] = c;
            dinv[i] = rsqrtf((float)(c + 1));  // +1 self-loop
        }
    }
    __syncthreads();
    for (int k = t; k < bc; k += 256) {
        int2 e = csr_tmp[bb + k];
        int pos = bb + atomicAdd(&off5[e.x - d0], 1);
        csr_s[pos] = e.y;
    }
}

// expand csr_s -> csr_sw = {src, dinv[src]} (coalesced r/w; random reads hit 400KB dinv table)
__global__ __launch_bounds__(256) void k_csrw(const int* __restrict__ csr_s, const float* __restrict__ dinv,
                                              int2* __restrict__ csr_sw, int E) {
    for (long e = (long)blockIdx.x * 256 + threadIdx.x; e < E; e += (long)gridDim.x * 256) {
        int s = csr_s[e];
        int2 q;
        q.x = s;
        q.y = __float_as_int(dinv[s]);
        csr_sw[e] = q;
    }
}

// ---------------- CSR gather-aggregate ----------------
// out[i] = dinv_i * ( sum_e w_e * x[src_e] + dinv_i * x[i] )  [+ bias/BN/ELU epilogue]
template<int F, bool L1EPI>
__global__ __launch_bounds__(256) void k_gather(const int* __restrict__ base, const int* __restrict__ cnt,
                                                const int2* __restrict__ csr_sw,
                                                const float* __restrict__ dinv, const float* __restrict__ xin,
                                                const float* __restrict__ b, const float* __restrict__ g,
                                                const float* __restrict__ be, const float* __restrict__ rm,
                                                const float* __restrict__ rv, float* __restrict__ out, int n) {
    constexpr int C = F / 4;          // float4 lanes per node
    constexpr int NPB = 256 / C;      // nodes per block
    int lane = threadIdx.x % C;
    int nl = threadIdx.x / C;
    int i = blockIdx.x * NPB + nl;
    if (i >= n) return;
    int k = base[i];
    int kend = k + cnt[i];
    float di = dinv[i];
    const float4* X4 = reinterpret_cast<const float4*>(xin);
    float4 acc = {0.f, 0.f, 0.f, 0.f};
    float4 acc2 = {0.f, 0.f, 0.f, 0.f};
    for (; k + 1 < kend; k += 2) {
        int2 ea = csr_sw[k];
        int2 eb = csr_sw[k + 1];
        float wa = __int_as_float(ea.y);
        float wb = __int_as_float(eb.y);
        float4 xa = X4[(long)ea.x * C + lane];
        float4 xb = X4[(long)eb.x * C + lane];
        acc.x += wa * xa.x; acc.y += wa * xa.y; acc.z += wa * xa.z; acc.w += wa * xa.w;
        acc2.x += wb * xb.x; acc2.y += wb * xb.y; acc2.z += wb * xb.z; acc2.w += wb * xb.w;
    }
    if (k < kend) {
        int2 ea = csr_sw[k];
        float wa = __int_as_float(ea.y);
        float4 xa = X4[(long)ea.x * C + lane];
        acc.x += wa * xa.x; acc.y += wa * xa.y; acc.z += wa * xa.z; acc.w += wa * xa.w;
    }
    acc.x += acc2.x; acc.y += acc2.y; acc.z += acc2.z; acc.w += acc2.w;
    float4 xs = X4[(long)i * C + lane];
    float4 o;
    o.x = di * (acc.x + di * xs.x);
    o.y = di * (acc.y + di * xs.y);
    o.z = di * (acc.z + di * xs.z);
    o.w = di * (acc.w + di * xs.w);
    if (L1EPI) {
        float4 bb = reinterpret_cast<const float4*>(b)[lane];
        float4 gg = reinterpret_cast<const float4*>(g)[lane];
        float4 ee = reinterpret_cast<const float4*>(be)[lane];
        float4 mm = reinterpret_cast<const float4*>(rm)[lane];
        float4 vv = reinterpret_cast<const float4*>(rv)[lane];
        o.x = elu_f((o.x + bb.x - mm.x) * rsqrtf(vv.x + EPSF) * gg.x + ee.x);
        o.y = elu_f((o.y + bb.y - mm.y) * rsqrtf(vv.y + EPSF) * gg.y + ee.y);
        o.z = elu_f((o.z + bb.z - mm.z) * rsqrtf(vv.z + EPSF) * gg.z + ee.z);
        o.w = elu_f((o.w + bb.w - mm.w) * rsqrtf(vv.w + EPSF) * gg.w + ee.w);
    }
    reinterpret_cast<float4*>(out)[(long)i * C + lane] = o;
}

// scalar gather for layer 4 + final sigmoid(elu(.)) epilogue, writes d_out
__global__ __launch_bounds__(256) void k_gather1_final(const int* __restrict__ base, const int* __restrict__ cnt,
                                                       const int2* __restrict__ csr_sw,
                                                       const float* __restrict__ dinv, const float* __restrict__ y,
                                                       const float* __restrict__ b4, float* __restrict__ out, int n) {
    int i = blockIdx.x * 256 + threadIdx.x;
    if (i >= n) return;
    int k = base[i];
    int kend = k + cnt[i];
    float di = dinv[i];
    float acc = 0.f;
    for (; k < kend; ++k) {
        int2 ea = csr_sw[k];
        acc += __int_as_float(ea.y) * y[ea.x];
    }
    float v = di * (acc + di * y[i]) + b4[0];
    v = elu_f(v);
    out[i] = 1.f / (1.f + expf(-v));
}

// ---------------- register-tiled dense GEMM ----------------
// Thread: TR=4 rows x 4 fouts. W staged in LDS, one ds_read_b128 per k shared by 4 rows.
// __launch_bounds__(256,4): cap VGPR at 128 so >=4 waves/SIMD (R3 lesson).
// #pragma unroll 2 keeps only 2 k0-iterations of X loads in flight.
template<int DIN, int DOUT, bool BN, bool FUSE_DOT>
__global__ __launch_bounds__(256, 4) void k_gemm_rt(const float* __restrict__ X, const float* __restrict__ W,
                                                    const float* __restrict__ b, const float* __restrict__ g,
                                                    const float* __restrict__ be, const float* __restrict__ rm,
                                                    const float* __restrict__ rv, const float* __restrict__ W4,
                                                    float* __restrict__ Y, int n) {
    constexpr int TR = 4;
    constexpr int FL = DOUT / 4;       // fout-lane groups
    constexpr int RG = 256 / FL;       // row-groups per block
    constexpr int BR = RG * TR;        // rows per block
    __shared__ float Wl[DIN * DOUT];
    for (int idx = threadIdx.x; idx < DIN * DOUT; idx += 256) Wl[idx] = W[idx];
    __syncthreads();
    const int fl = threadIdx.x % FL;
    const int rg = threadIdx.x / FL;
    const int f0 = fl * 4;
    const long r0 = (long)blockIdx.x * BR + (long)rg * TR;

    float4 z; z.x = z.y = z.z = z.w = 0.f;
    float4 acc[TR];
    #pragma unroll
    for (int r = 0; r < TR; ++r) acc[r] = z;

    #pragma unroll 2
    for (int k0 = 0; k0 < DIN; k0 += 4) {
        float4 xv[TR];
        #pragma unroll
        for (int r = 0; r < TR; ++r) {
            long row = r0 + r;
            xv[r] = (row < n) ? *reinterpret_cast<const float4*>(X + row * DIN + k0) : z;
        }
        #pragma unroll
        for (int kk = 0; kk < 4; ++kk) {
            float4 w4 = *reinterpret_cast<const float4*>(&Wl[(k0 + kk) * DOUT + f0]);
            #pragma unroll
            for (int r = 0; r < TR; ++r) {
                float xs = (kk == 0) ? xv[r].x : (kk == 1) ? xv[r].y : (kk == 2) ? xv[r].z : xv[r].w;
                acc[r].x += xs * w4.x;
                acc[r].y += xs * w4.y;
                acc[r].z += xs * w4.z;
                acc[r].w += xs * w4.w;
            }
        }
    }

    float4 bias = z, scale = z, shift = z, w4d = z;
    if (BN) {
        bias = *reinterpret_cast<const float4*>(b + f0);
        float4 gg = *reinterpret_cast<const float4*>(g + f0);
        float4 ee = *reinterpret_cast<const float4*>(be + f0);
        float4 mm = *reinterpret_cast<const float4*>(rm + f0);
        float4 vv = *reinterpret_cast<const float4*>(rv + f0);
        scale.x = gg.x * rsqrtf(vv.x + EPSF); shift.x = ee.x - mm.x * scale.x;
        scale.y = gg.y * rsqrtf(vv.y + EPSF); shift.y = ee.y - mm.y * scale.y;
        scale.z = gg.z * rsqrtf(vv.z + EPSF); shift.z = ee.z - mm.z * scale.z;
        scale.w = gg.w * rsqrtf(vv.w + EPSF); shift.w = ee.w - mm.w * scale.w;
    }
    if (FUSE_DOT) w4d = *reinterpret_cast<const float4*>(W4 + f0);

    #pragma unroll
    for (int r = 0; r < TR; ++r) {
        long row = r0 + r;
        if (row >= n) continue;
        float4 v = acc[r];
        if (BN) {
            v.x = elu_f((v.x + bias.x) * scale.x + shift.x);
            v.y = elu_f((v.y + bias.y) * scale.y + shift.y);
            v.z = elu_f((v.z + bias.z) * scale.z + shift.z);
            v.w = elu_f((v.w + bias.w) * scale.w + shift.w);
        }
        if (FUSE_DOT) {
            float p = v.x * w4d.x + v.y * w4d.y + v.z * w4d.z + v.w * w4d.w;
            #pragma unroll
            for (int m = 1; m < FL; m <<= 1) p += __shfl_xor(p, m, 64);
            if (fl == 0) Y[row] = p;
        } else {
            *reinterpret_cast<float4*>(Y + row * DOUT + f0) = v;
        }
    }
}

// ---------------- launch ----------------

extern "C" void kernel_launch(void* const* d_in, const int* in_sizes, int n_in,
                              void* d_out, int out_size, void* d_ws, size_t ws_size,
                              hipStream_t stream) {
    const float* x   = (const float*)d_in[0];
    const int*   edg = (const int*)d_in[1];
    const float* W1 = (const float*)d_in[2];
    const float* b1 = (const float*)d_in[3];
    const float* W2 = (const float*)d_in[4];
    const float* b2 = (const float*)d_in[5];
    const float* W3 = (const float*)d_in[6];
    const float* b3 = (const float*)d_in[7];
    const float* W4 = (const float*)d_in[8];
    const float* b4 = (const float*)d_in[9];
    const float* g1  = (const float*)d_in[10];
    const float* be1 = (const float*)d_in[11];
    const float* rm1 = (const float*)d_in[12];
    const float* rv1 = (const float*)d_in[13];
    const float* g2  = (const float*)d_in[14];
    const float* be2 = (const float*)d_in[15];
    const float* rm2 = (const float*)d_in[16];
    const float* rv2 = (const float*)d_in[17];
    const float* g3  = (const float*)d_in[18];
    const float* be3 = (const float*)d_in[19];
    const float* rm3 = (const float*)d_in[20];
    const float* rv3 = (const float*)d_in[21];
    float* out = (float*)d_out;

    const int N = in_sizes[0] / 64;
    const int E = in_sizes[1] / 2;
    const int* src = edg;
    const int* dst = edg + E;
    const int NB_BKT = (N + BKT_NODES - 1) / BKT_NODES;   // 196 for N=100000 (<=256)
    const int NTILES = (E + TILE_E - 1) / TILE_E;

    // workspace layout
    int*   bkt_cnt = (int*)d_ws;                    // 256
    int*   bbase   = bkt_cnt + 256;                 // 256
    int*   cursor  = bbase + 256;                   // 256
    int*   cnt     = cursor + 256;                  // N
    int*   base    = cnt + N;                       // N
    float* dinv    = (float*)(base + N);            // N
    int2*  csr_sw  = (int2*)(dinv + N);             // E int2 (8B-aligned: 768+3N ints, N even)
    float* featA   = (float*)(csr_sw + E);          // N*64
    float* featB   = featA + (size_t)N * 64;        // N*64
    // aliases live only during CSR build (dead before featA/featB are written):
    int2*  csr_tmp = (int2*)featA;                  // E int2 (12.8MB <= 25.6MB)
    int*   csr_s   = (int*)featB;                   // E int  (6.4MB <= 25.6MB)

    auto nb = [](long total) { return (int)((total + 255) / 256); };

    // bucketed CSR build (per call: workspace re-poisoned every launch)
    k_zero<<<1, 256, 0, stream>>>(bkt_cnt, 256);
    k_bhist<<<512, 256, 0, stream>>>(dst, bkt_cnt, E);
    k_bscan<<<1, 256, 0, stream>>>(bkt_cnt, bbase, cursor);
    k_bpart<<<NTILES, 256, 0, stream>>>(src, dst, cursor, csr_tmp, E);
    k_bfine<<<NB_BKT, 256, 0, stream>>>(csr_tmp, bbase, bkt_cnt, cnt, base, dinv, csr_s, N);
    k_csrw<<<2048, 256, 0, stream>>>(csr_s, dinv, csr_sw, E);

    // Layer 1 (64->32): GEMM, then gather-agg fused with bias+BN+ELU
    k_gemm_rt<64, 32, false, false><<<(N + 127) / 128, 256, 0, stream>>>(
        x, W1, nullptr, nullptr, nullptr, nullptr, nullptr, nullptr, featA, N);
    k_gather<32, true><<<(N + 31) / 32, 256, 0, stream>>>(base, cnt, csr_sw, dinv, featA,
                                                          b1, g1, be1, rm1, rv1, featB, N);

    // Layer 2 (32->64): gather-agg first, then fused GEMM+bias+BN+ELU
    k_gather<32, false><<<(N + 31) / 32, 256, 0, stream>>>(base, cnt, csr_sw, dinv, featB,
                                                           nullptr, nullptr, nullptr, nullptr, nullptr, featA, N);
    k_gemm_rt<32, 64, true, false><<<(N + 63) / 64, 256, 0, stream>>>(
        featA, W2, b2, g2, be2, rm2, rv2, nullptr, featB, N);

    // Layer 3 (64->128): gather-agg, then fused GEMM+bias+BN+ELU+dot(W4) -> y in featB
    k_gather<64, false><<<(N + 15) / 16, 256, 0, stream>>>(base, cnt, csr_sw, dinv, featB,
                                                           nullptr, nullptr, nullptr, nullptr, nullptr, featA, N);
    k_gemm_rt<64, 128, true, true><<<(N + 31) / 32, 256, 0, stream>>>(
        featA, W3, b3, g3, be3, rm3, rv3, W4, featB, N);

    // Layer 4 (128->1): scalar gather-agg fused with bias + sigmoid(elu(.)) -> d_out
    k_gather1_final<<<nb(N), 256, 0, stream>>>(base, cnt, csr_sw, dinv, featB, b4, out, N);
}

// Round 9
// 398.986 us; speedup vs baseline: 1.2794x; 1.0587x over previous
//
#include <hip/hip_runtime.h>

#define EPSF 1e-5f
#define BKT_SHIFT 9
#define BKT_NODES 512              // nodes per bucket
#define TILE_E 4096                // edges per k_bpart block

__device__ __forceinline__ float elu_f(float x) { return x > 0.f ? x : expm1f(x); }

// ---------------- bucketed CSR build ----------------

__global__ __launch_bounds__(256) void k_zero(int* p, int n) {
    int i = blockIdx.x * 256 + threadIdx.x;
    if (i < n) p[i] = 0;
}

// coarse bucket histogram (bucket = dst>>9), LDS-staged
__global__ __launch_bounds__(256) void k_bhist(const int* __restrict__ dst, int* __restrict__ bkt_cnt, int E) {
    __shared__ int h[256];
    int t = threadIdx.x;
    h[t] = 0;
    __syncthreads();
    for (long e = (long)blockIdx.x * 256 + t; e < E; e += (long)gridDim.x * 256)
        atomicAdd(&h[dst[e] >> BKT_SHIFT], 1);
    __syncthreads();
    if (h[t]) atomicAdd(&bkt_cnt[t], h[t]);
}

// exclusive scan of 256 bucket counts -> bbase; cursor = bbase copy
__global__ __launch_bounds__(256) void k_bscan(const int* __restrict__ bkt_cnt, int* __restrict__ bbase,
                                               int* __restrict__ cursor) {
    __shared__ int sh[256];
    int t = threadIdx.x;
    int v = bkt_cnt[t];
    sh[t] = v;
    __syncthreads();
    for (int off = 1; off < 256; off <<= 1) {
        int add = (t >= off) ? sh[t - off] : 0;
        __syncthreads();
        sh[t] += add;
        __syncthreads();
    }
    int ex = sh[t] - v;
    bbase[t] = ex;
    cursor[t] = ex;
}

// partition edges into bucket-contiguous csr_tmp = {dst, src}.
// Per 4096-edge tile: LDS rank within (tile,bucket), one global atomicAdd per bucket,
// then writes land in ~21-entry contiguous runs (~full cache lines).
__global__ __launch_bounds__(256) void k_bpart(const int* __restrict__ src, const int* __restrict__ dst,
                                               int* __restrict__ cursor, int2* __restrict__ csr_tmp, int E) {
    __shared__ int hcnt[256];
    __shared__ int gbase[256];
    int t = threadIdx.x;
    long tile0 = (long)blockIdx.x * TILE_E;
    hcnt[t] = 0;
    __syncthreads();
    int d[16], s[16], rk[16];
    #pragma unroll
    for (int j = 0; j < 16; ++j) {
        long e = tile0 + j * 256 + t;
        if (e < E) {
            d[j] = dst[e];
            s[j] = src[e];
            rk[j] = atomicAdd(&hcnt[d[j] >> BKT_SHIFT], 1);
        }
    }
    __syncthreads();
    int c = hcnt[t];
    if (c) gbase[t] = atomicAdd(&cursor[t], c);
    __syncthreads();
    #pragma unroll
    for (int j = 0; j < 16; ++j) {
        long e = tile0 + j * 256 + t;
        if (e < E) {
            int2 q;
            q.x = d[j];
            q.y = s[j];
            csr_tmp[gbase[d[j] >> BKT_SHIFT] + rk[j]] = q;
        }
    }
}

// per-bucket fine CSR: 512-node LDS histogram + scan -> cnt/base/dinv (coalesced),
// then scatter src into the bucket's own (L2-hot, ~32KB) csr_s window.
__global__ __launch_bounds__(256) void k_bfine(const int2* __restrict__ csr_tmp, const int* __restrict__ bbase,
                                               const int* __restrict__ bkt_cnt, int* __restrict__ cnt,
                                               int* __restrict__ base, float* __restrict__ dinv,
                                               int* __restrict__ csr_s, int N) {
    __shared__ int cnt5[BKT_NODES];
    __shared__ int off5[BKT_NODES];
    __shared__ int sh[256];
    int b = blockIdx.x;
    int t = threadIdx.x;
    int d0 = b << BKT_SHIFT;
    int bb = bbase[b];
    int bc = bkt_cnt[b];
    cnt5[t] = 0;
    cnt5[t + 256] = 0;
    __syncthreads();
    for (int k = t; k < bc; k += 256) atomicAdd(&cnt5[csr_tmp[bb + k].x - d0], 1);
    __syncthreads();
    int v0 = cnt5[2 * t], v1 = cnt5[2 * t + 1];
    int p = v0 + v1;
    sh[t] = p;
    __syncthreads();
    for (int off = 1; off < 256; off <<= 1) {
        int add = (t >= off) ? sh[t - off] : 0;
        __syncthreads();
        sh[t] += add;
        __syncthreads();
    }
    int pre = sh[t] - p;
    off5[2 * t] = pre;
    off5[2 * t + 1] = pre + v0;
    #pragma unroll
    for (int j = 0; j < 2; ++j) {
        int idx = 2 * t + j;
        int i = d0 + idx;
        if (i < N) {
            int c = cnt5[idx];
            base[i] = bb + off5[idx];
            cnt[i] = c;
            dinv[i] = rsqrtf((float)(c + 1));  // +1 self-loop
        }
    }
    __syncthreads();
    for (int k = t; k < bc; k += 256) {
        int2 e = csr_tmp[bb + k];
        int pos = bb + atomicAdd(&off5[e.x - d0], 1);
        csr_s[pos] = e.y;
    }
}

// ---------------- CSR gather-aggregate (weightless: features pre-scaled by dinv) ----------------
// in  P[j] = dinv_j * val_j  (written by the producing GEMM/gather epilogue)
// out t_i  = dinv_i * ( sum_e P[src_e] + P[i] )
// L1EPI: out = dinv_i * elu(BN(t_i + b))   (pre-scaled for the NEXT gather)
template<int F, bool L1EPI>
__global__ __launch_bounds__(256) void k_gather(const int* __restrict__ base, const int* __restrict__ cnt,
                                                const int* __restrict__ csr_s,
                                                const float* __restrict__ dinv, const float* __restrict__ xin,
                                                const float* __restrict__ b, const float* __restrict__ g,
                                                const float* __restrict__ be, const float* __restrict__ rm,
                                                const float* __restrict__ rv, float* __restrict__ out, int n) {
    constexpr int C = F / 4;          // float4 lanes per node
    constexpr int NPB = 256 / C;      // nodes per block
    int lane = threadIdx.x % C;
    int nl = threadIdx.x / C;
    int i = blockIdx.x * NPB + nl;
    if (i >= n) return;
    int k = base[i];
    int kend = k + cnt[i];
    float di = dinv[i];
    const float4* X4 = reinterpret_cast<const float4*>(xin);
    float4 z = {0.f, 0.f, 0.f, 0.f};
    float4 a0 = z, a1 = z, a2 = z, a3 = z;
    // 4-deep: issue 4 index loads, then 4 row loads -> more MLP on the L2-miss path
    for (; k + 3 < kend; k += 4) {
        int s0 = csr_s[k], s1 = csr_s[k + 1], s2 = csr_s[k + 2], s3 = csr_s[k + 3];
        float4 x0 = X4[(long)s0 * C + lane];
        float4 x1 = X4[(long)s1 * C + lane];
        float4 x2 = X4[(long)s2 * C + lane];
        float4 x3 = X4[(long)s3 * C + lane];
        a0.x += x0.x; a0.y += x0.y; a0.z += x0.z; a0.w += x0.w;
        a1.x += x1.x; a1.y += x1.y; a1.z += x1.z; a1.w += x1.w;
        a2.x += x2.x; a2.y += x2.y; a2.z += x2.z; a2.w += x2.w;
        a3.x += x3.x; a3.y += x3.y; a3.z += x3.z; a3.w += x3.w;
    }
    for (; k < kend; ++k) {
        float4 xa = X4[(long)csr_s[k] * C + lane];
        a0.x += xa.x; a0.y += xa.y; a0.z += xa.z; a0.w += xa.w;
    }
    float4 xs = X4[(long)i * C + lane];   // self term P[i]
    float4 o;
    o.x = di * (a0.x + a1.x + a2.x + a3.x + xs.x);
    o.y = di * (a0.y + a1.y + a2.y + a3.y + xs.y);
    o.z = di * (a0.z + a1.z + a2.z + a3.z + xs.z);
    o.w = di * (a0.w + a1.w + a2.w + a3.w + xs.w);
    if (L1EPI) {
        float4 bb = reinterpret_cast<const float4*>(b)[lane];
        float4 gg = reinterpret_cast<const float4*>(g)[lane];
        float4 ee = reinterpret_cast<const float4*>(be)[lane];
        float4 mm = reinterpret_cast<const float4*>(rm)[lane];
        float4 vv = reinterpret_cast<const float4*>(rv)[lane];
        o.x = di * elu_f((o.x + bb.x - mm.x) * rsqrtf(vv.x + EPSF) * gg.x + ee.x);
        o.y = di * elu_f((o.y + bb.y - mm.y) * rsqrtf(vv.y + EPSF) * gg.y + ee.y);
        o.z = di * elu_f((o.z + bb.z - mm.z) * rsqrtf(vv.z + EPSF) * gg.z + ee.z);
        o.w = di * elu_f((o.w + bb.w - mm.w) * rsqrtf(vv.w + EPSF) * gg.w + ee.w);
    }
    reinterpret_cast<float4*>(out)[(long)i * C + lane] = o;
}

// scalar gather for layer 4 (y pre-scaled by dinv) + bias + sigmoid(elu(.)) -> d_out
__global__ __launch_bounds__(256) void k_gather1_final(const int* __restrict__ base, const int* __restrict__ cnt,
                                                       const int* __restrict__ csr_s,
                                                       const float* __restrict__ dinv, const float* __restrict__ y,
                                                       const float* __restrict__ b4, float* __restrict__ out, int n) {
    int i = blockIdx.x * 256 + threadIdx.x;
    if (i >= n) return;
    int k = base[i];
    int kend = k + cnt[i];
    float di = dinv[i];
    float acc = 0.f;
    for (; k < kend; ++k) acc += y[csr_s[k]];
    float v = di * (acc + y[i]) + b4[0];
    v = elu_f(v);
    out[i] = 1.f / (1.f + expf(-v));
}

// ---------------- register-tiled dense GEMM ----------------
// Thread: TR=4 rows x 4 fouts. W staged in LDS, one ds_read_b128 per k shared by 4 rows.
// __launch_bounds__(256,4): cap VGPR at 128 so >=4 waves/SIMD (R3 lesson).
// #pragma unroll 2 keeps only 2 k0-iterations of X loads in flight.
// SCALE_DINV: multiply the written value by dinv[row] (pre-scale for the next gather).
template<int DIN, int DOUT, bool BN, bool FUSE_DOT, bool SCALE_DINV>
__global__ __launch_bounds__(256, 4) void k_gemm_rt(const float* __restrict__ X, const float* __restrict__ W,
                                                    const float* __restrict__ b, const float* __restrict__ g,
                                                    const float* __restrict__ be, const float* __restrict__ rm,
                                                    const float* __restrict__ rv, const float* __restrict__ W4,
                                                    const float* __restrict__ dinv,
                                                    float* __restrict__ Y, int n) {
    constexpr int TR = 4;
    constexpr int FL = DOUT / 4;       // fout-lane groups
    constexpr int RG = 256 / FL;       // row-groups per block
    constexpr int BR = RG * TR;        // rows per block
    __shared__ float Wl[DIN * DOUT];
    for (int idx = threadIdx.x; idx < DIN * DOUT; idx += 256) Wl[idx] = W[idx];
    __syncthreads();
    const int fl = threadIdx.x % FL;
    const int rg = threadIdx.x / FL;
    const int f0 = fl * 4;
    const long r0 = (long)blockIdx.x * BR + (long)rg * TR;

    float4 z; z.x = z.y = z.z = z.w = 0.f;
    float4 acc[TR];
    #pragma unroll
    for (int r = 0; r < TR; ++r) acc[r] = z;

    #pragma unroll 2
    for (int k0 = 0; k0 < DIN; k0 += 4) {
        float4 xv[TR];
        #pragma unroll
        for (int r = 0; r < TR; ++r) {
            long row = r0 + r;
            xv[r] = (row < n) ? *reinterpret_cast<const float4*>(X + row * DIN + k0) : z;
        }
        #pragma unroll
        for (int kk = 0; kk < 4; ++kk) {
            float4 w4 = *reinterpret_cast<const float4*>(&Wl[(k0 + kk) * DOUT + f0]);
            #pragma unroll
            for (int r = 0; r < TR; ++r) {
                float xs = (kk == 0) ? xv[r].x : (kk == 1) ? xv[r].y : (kk == 2) ? xv[r].z : xv[r].w;
                acc[r].x += xs * w4.x;
                acc[r].y += xs * w4.y;
                acc[r].z += xs * w4.z;
                acc[r].w += xs * w4.w;
            }
        }
    }

    float4 bias = z, scale = z, shift = z, w4d = z;
    if (BN) {
        bias = *reinterpret_cast<const float4*>(b + f0);
        float4 gg = *reinterpret_cast<const float4*>(g + f0);
        float4 ee = *reinterpret_cast<const float4*>(be + f0);
        float4 mm = *reinterpret_cast<const float4*>(rm + f0);
        float4 vv = *reinterpret_cast<const float4*>(rv + f0);
        scale.x = gg.x * rsqrtf(vv.x + EPSF); shift.x = ee.x - mm.x * scale.x;
        scale.y = gg.y * rsqrtf(vv.y + EPSF); shift.y = ee.y - mm.y * scale.y;
        scale.z = gg.z * rsqrtf(vv.z + EPSF); shift.z = ee.z - mm.z * scale.z;
        scale.w = gg.w * rsqrtf(vv.w + EPSF); shift.w = ee.w - mm.w * scale.w;
    }
    if (FUSE_DOT) w4d = *reinterpret_cast<const float4*>(W4 + f0);

    #pragma unroll
    for (int r = 0; r < TR; ++r) {
        long row = r0 + r;
        if (row >= n) continue;
        float4 v = acc[r];
        if (BN) {
            v.x = elu_f((v.x + bias.x) * scale.x + shift.x);
            v.y = elu_f((v.y + bias.y) * scale.y + shift.y);
            v.z = elu_f((v.z + bias.z) * scale.z + shift.z);
            v.w = elu_f((v.w + bias.w) * scale.w + shift.w);
        }
        float dv = SCALE_DINV ? dinv[row] : 1.f;
        if (FUSE_DOT) {
            float p = v.x * w4d.x + v.y * w4d.y + v.z * w4d.z + v.w * w4d.w;
            #pragma unroll
            for (int m = 1; m < FL; m <<= 1) p += __shfl_xor(p, m, 64);
            if (fl == 0) Y[row] = dv * p;
        } else {
            if (SCALE_DINV) { v.x *= dv; v.y *= dv; v.z *= dv; v.w *= dv; }
            *reinterpret_cast<float4*>(Y + row * DOUT + f0) = v;
        }
    }
}

// ---------------- launch ----------------

extern "C" void kernel_launch(void* const* d_in, const int* in_sizes, int n_in,
                              void* d_out, int out_size, void* d_ws, size_t ws_size,
                              hipStream_t stream) {
    const float* x   = (const float*)d_in[0];
    const int*   edg = (const int*)d_in[1];
    const float* W1 = (const float*)d_in[2];
    const float* b1 = (const float*)d_in[3];
    const float* W2 = (const float*)d_in[4];
    const float* b2 = (const float*)d_in[5];
    const float* W3 = (const float*)d_in[6];
    const float* b3 = (const float*)d_in[7];
    const float* W4 = (const float*)d_in[8];
    const float* b4 = (const float*)d_in[9];
    const float* g1  = (const float*)d_in[10];
    const float* be1 = (const float*)d_in[11];
    const float* rm1 = (const float*)d_in[12];
    const float* rv1 = (const float*)d_in[13];
    const float* g2  = (const float*)d_in[14];
    const float* be2 = (const float*)d_in[15];
    const float* rm2 = (const float*)d_in[16];
    const float* rv2 = (const float*)d_in[17];
    const float* g3  = (const float*)d_in[18];
    const float* be3 = (const float*)d_in[19];
    const float* rm3 = (const float*)d_in[20];
    const float* rv3 = (const float*)d_in[21];
    float* out = (float*)d_out;

    const int N = in_sizes[0] / 64;
    const int E = in_sizes[1] / 2;
    const int* src = edg;
    const int* dst = edg + E;
    const int NB_BKT = (N + BKT_NODES - 1) / BKT_NODES;   // 196 for N=100000 (<=256)
    const int NTILES = (E + TILE_E - 1) / TILE_E;

    // workspace layout
    int*   bkt_cnt = (int*)d_ws;                    // 256
    int*   bbase   = bkt_cnt + 256;                 // 256
    int*   cursor  = bbase + 256;                   // 256
    int*   cnt     = cursor + 256;                  // N
    int*   base    = cnt + N;                       // N
    float* dinv    = (float*)(base + N);            // N
    int*   csr_s   = (int*)(dinv + N);              // E (permanent: gathers read it)
    float* featA   = (float*)(csr_s + E);           // N*64
    float* featB   = featA + (size_t)N * 64;        // N*64
    // alias lives only during CSR build (dead before featA is written):
    int2*  csr_tmp = (int2*)featA;                  // E int2 (12.8MB <= 25.6MB)

    auto nb = [](long total) { return (int)((total + 255) / 256); };

    // bucketed CSR build (per call: workspace re-poisoned every launch)
    k_zero<<<1, 256, 0, stream>>>(bkt_cnt, 256);
    k_bhist<<<512, 256, 0, stream>>>(dst, bkt_cnt, E);
    k_bscan<<<1, 256, 0, stream>>>(bkt_cnt, bbase, cursor);
    k_bpart<<<NTILES, 256, 0, stream>>>(src, dst, cursor, csr_tmp, E);
    k_bfine<<<NB_BKT, 256, 0, stream>>>(csr_tmp, bbase, bkt_cnt, cnt, base, dinv, csr_s, N);

    // Layer 1 (64->32): GEMM (pre-scaled by dinv), then gather fused with bias+BN+ELU (+pre-scale)
    k_gemm_rt<64, 32, false, false, true><<<(N + 127) / 128, 256, 0, stream>>>(
        x, W1, nullptr, nullptr, nullptr, nullptr, nullptr, nullptr, dinv, featB, N);
    k_gather<32, true><<<(N + 31) / 32, 256, 0, stream>>>(base, cnt, csr_s, dinv, featB,
                                                          b1, g1, be1, rm1, rv1, featA, N);

    // Layer 2 (32->64): gather (plain agg), then fused GEMM+bias+BN+ELU (+pre-scale)
    k_gather<32, false><<<(N + 31) / 32, 256, 0, stream>>>(base, cnt, csr_s, dinv, featA,
                                                           nullptr, nullptr, nullptr, nullptr, nullptr, featB, N);
    k_gemm_rt<32, 64, true, false, true><<<(N + 63) / 64, 256, 0, stream>>>(
        featB, W2, b2, g2, be2, rm2, rv2, nullptr, dinv, featA, N);

    // Layer 3 (64->128): gather (plain agg), then fused GEMM+bias+BN+ELU+dot(W4) (+pre-scale) -> y
    k_gather<64, false><<<(N + 15) / 16, 256, 0, stream>>>(base, cnt, csr_s, dinv, featA,
                                                           nullptr, nullptr, nullptr, nullptr, nullptr, featB, N);
    k_gemm_rt<64, 128, true, true, true><<<(N + 31) / 32, 256, 0, stream>>>(
        featB, W3, b3, g3, be3, rm3, rv3, W4, dinv, featA, N);

    // Layer 4 (128->1): scalar gather + bias + sigmoid(elu(.)) -> d_out
    k_gather1_final<<<nb(N), 256, 0, stream>>>(base, cnt, csr_s, dinv, featA, b4, out, N);
}

// Round 10
// 366.040 us; speedup vs baseline: 1.3945x; 1.0900x over previous
//
#include <hip/hip_runtime.h>
#include <hip/hip_fp16.h>

#define EPSF 1e-5f
#define BKT_SHIFT 9
#define BKT_NODES 512              // nodes per bucket
#define TILE_E 4096                // edges per k_bpart block

__device__ __forceinline__ float elu_f(float x) { return x > 0.f ? x : expm1f(x); }

// 4 halves <-> float4 (single 8B load/store on the fp16 side, f32 accumulation)
__device__ __forceinline__ float4 h4_to_f4(uint2 u) {
    __half2 a = *reinterpret_cast<const __half2*>(&u.x);
    __half2 b = *reinterpret_cast<const __half2*>(&u.y);
    float2 fa = __half22float2(a);
    float2 fb = __half22float2(b);
    return make_float4(fa.x, fa.y, fb.x, fb.y);
}
__device__ __forceinline__ uint2 f4_to_h4(float4 v) {
    __half2 a = __floats2half2_rn(v.x, v.y);
    __half2 b = __floats2half2_rn(v.z, v.w);
    uint2 u;
    u.x = *reinterpret_cast<unsigned*>(&a);
    u.y = *reinterpret_cast<unsigned*>(&b);
    return u;
}

// ---------------- bucketed CSR build ----------------

__global__ __launch_bounds__(256) void k_zero(int* p, int n) {
    int i = blockIdx.x * 256 + threadIdx.x;
    if (i < n) p[i] = 0;
}

// coarse bucket histogram (bucket = dst>>9), LDS-staged
__global__ __launch_bounds__(256) void k_bhist(const int* __restrict__ dst, int* __restrict__ bkt_cnt, int E) {
    __shared__ int h[256];
    int t = threadIdx.x;
    h[t] = 0;
    __syncthreads();
    for (long e = (long)blockIdx.x * 256 + t; e < E; e += (long)gridDim.x * 256)
        atomicAdd(&h[dst[e] >> BKT_SHIFT], 1);
    __syncthreads();
    if (h[t]) atomicAdd(&bkt_cnt[t], h[t]);
}

// exclusive scan of 256 bucket counts -> bbase; cursor = bbase copy
__global__ __launch_bounds__(256) void k_bscan(const int* __restrict__ bkt_cnt, int* __restrict__ bbase,
                                               int* __restrict__ cursor) {
    __shared__ int sh[256];
    int t = threadIdx.x;
    int v = bkt_cnt[t];
    sh[t] = v;
    __syncthreads();
    for (int off = 1; off < 256; off <<= 1) {
        int add = (t >= off) ? sh[t - off] : 0;
        __syncthreads();
        sh[t] += add;
        __syncthreads();
    }
    int ex = sh[t] - v;
    bbase[t] = ex;
    cursor[t] = ex;
}

// partition edges into bucket-contiguous csr_tmp = {dst, src}.
__global__ __launch_bounds__(256) void k_bpart(const int* __restrict__ src, const int* __restrict__ dst,
                                               int* __restrict__ cursor, int2* __restrict__ csr_tmp, int E) {
    __shared__ int hcnt[256];
    __shared__ int gbase[256];
    int t = threadIdx.x;
    long tile0 = (long)blockIdx.x * TILE_E;
    hcnt[t] = 0;
    __syncthreads();
    int d[16], s[16], rk[16];
    #pragma unroll
    for (int j = 0; j < 16; ++j) {
        long e = tile0 + j * 256 + t;
        if (e < E) {
            d[j] = dst[e];
            s[j] = src[e];
            rk[j] = atomicAdd(&hcnt[d[j] >> BKT_SHIFT], 1);
        }
    }
    __syncthreads();
    int c = hcnt[t];
    if (c) gbase[t] = atomicAdd(&cursor[t], c);
    __syncthreads();
    #pragma unroll
    for (int j = 0; j < 16; ++j) {
        long e = tile0 + j * 256 + t;
        if (e < E) {
            int2 q;
            q.x = d[j];
            q.y = s[j];
            csr_tmp[gbase[d[j] >> BKT_SHIFT] + rk[j]] = q;
        }
    }
}

// per-bucket fine CSR: 512-node LDS histogram + scan -> cnt/base/dinv (coalesced),
// then scatter src into the bucket's own (L2-hot) csr_s window.
__global__ __launch_bounds__(256) void k_bfine(const int2* __restrict__ csr_tmp, const int* __restrict__ bbase,
                                               const int* __restrict__ bkt_cnt, int* __restrict__ cnt,
                                               int* __restrict__ base, float* __restrict__ dinv,
                                               int* __restrict__ csr_s, int N) {
    __shared__ int cnt5[BKT_NODES];
    __shared__ int off5[BKT_NODES];
    __shared__ int sh[256];
    int b = blockIdx.x;
    int t = threadIdx.x;
    int d0 = b << BKT_SHIFT;
    int bb = bbase[b];
    int bc = bkt_cnt[b];
    cnt5[t] = 0;
    cnt5[t + 256] = 0;
    __syncthreads();
    for (int k = t; k < bc; k += 256) atomicAdd(&cnt5[csr_tmp[bb + k].x - d0], 1);
    __syncthreads();
    int v0 = cnt5[2 * t], v1 = cnt5[2 * t + 1];
    int p = v0 + v1;
    sh[t] = p;
    __syncthreads();
    for (int off = 1; off < 256; off <<= 1) {
        int add = (t >= off) ? sh[t - off] : 0;
        __syncthreads();
        sh[t] += add;
        __syncthreads();
    }
    int pre = sh[t] - p;
    off5[2 * t] = pre;
    off5[2 * t + 1] = pre + v0;
    #pragma unroll
    for (int j = 0; j < 2; ++j) {
        int idx = 2 * t + j;
        int i = d0 + idx;
        if (i < N) {
            int c = cnt5[idx];
            base[i] = bb + off5[idx];
            cnt[i] = c;
            dinv[i] = rsqrtf((float)(c + 1));  // +1 self-loop
        }
    }
    __syncthreads();
    for (int k = t; k < bc; k += 256) {
        int2 e = csr_tmp[bb + k];
        int pos = bb + atomicAdd(&off5[e.x - d0], 1);
        csr_s[pos] = e.y;
    }
}

// ---------------- CSR gather-aggregate (weightless: features pre-scaled by dinv) ----------------
// in  P[j] = dinv_j * val_j ; out t_i = dinv_i * ( sum_e P[src_e] + P[i] )
// L1EPI: out = dinv_i * elu(BN(t_i + b))  (pre-scaled for the NEXT gather)
// HIN/HOUT: fp16 feature rows (f32 accumulation) to halve the 8x-per-XCD refetch bytes.
template<int F, bool L1EPI, bool HIN, bool HOUT>
__global__ __launch_bounds__(256) void k_gather(const int* __restrict__ base, const int* __restrict__ cnt,
                                                const int* __restrict__ csr_s,
                                                const float* __restrict__ dinv, const void* __restrict__ xin,
                                                const float* __restrict__ b, const float* __restrict__ g,
                                                const float* __restrict__ be, const float* __restrict__ rm,
                                                const float* __restrict__ rv, void* __restrict__ out, int n) {
    constexpr int C = F / 4;          // 4-elem lanes per node
    constexpr int NPB = 256 / C;      // nodes per block
    int lane = threadIdx.x % C;
    int nl = threadIdx.x / C;
    int i = blockIdx.x * NPB + nl;
    if (i >= n) return;
    int k = base[i];
    int kend = k + cnt[i];
    float di = dinv[i];
    const float4* XF = reinterpret_cast<const float4*>(xin);
    const uint2*  XH = reinterpret_cast<const uint2*>(xin);
    float4 z = {0.f, 0.f, 0.f, 0.f};
    float4 a0 = z, a1 = z, a2 = z, a3 = z;
    for (; k + 3 < kend; k += 4) {
        int s0 = csr_s[k], s1 = csr_s[k + 1], s2 = csr_s[k + 2], s3 = csr_s[k + 3];
        float4 x0 = HIN ? h4_to_f4(XH[(long)s0 * C + lane]) : XF[(long)s0 * C + lane];
        float4 x1 = HIN ? h4_to_f4(XH[(long)s1 * C + lane]) : XF[(long)s1 * C + lane];
        float4 x2 = HIN ? h4_to_f4(XH[(long)s2 * C + lane]) : XF[(long)s2 * C + lane];
        float4 x3 = HIN ? h4_to_f4(XH[(long)s3 * C + lane]) : XF[(long)s3 * C + lane];
        a0.x += x0.x; a0.y += x0.y; a0.z += x0.z; a0.w += x0.w;
        a1.x += x1.x; a1.y += x1.y; a1.z += x1.z; a1.w += x1.w;
        a2.x += x2.x; a2.y += x2.y; a2.z += x2.z; a2.w += x2.w;
        a3.x += x3.x; a3.y += x3.y; a3.z += x3.z; a3.w += x3.w;
    }
    for (; k < kend; ++k) {
        int s0 = csr_s[k];
        float4 xa = HIN ? h4_to_f4(XH[(long)s0 * C + lane]) : XF[(long)s0 * C + lane];
        a0.x += xa.x; a0.y += xa.y; a0.z += xa.z; a0.w += xa.w;
    }
    float4 xs = HIN ? h4_to_f4(XH[(long)i * C + lane]) : XF[(long)i * C + lane];  // self term
    float4 o;
    o.x = di * (a0.x + a1.x + a2.x + a3.x + xs.x);
    o.y = di * (a0.y + a1.y + a2.y + a3.y + xs.y);
    o.z = di * (a0.z + a1.z + a2.z + a3.z + xs.z);
    o.w = di * (a0.w + a1.w + a2.w + a3.w + xs.w);
    if (L1EPI) {
        float4 bb = reinterpret_cast<const float4*>(b)[lane];
        float4 gg = reinterpret_cast<const float4*>(g)[lane];
        float4 ee = reinterpret_cast<const float4*>(be)[lane];
        float4 mm = reinterpret_cast<const float4*>(rm)[lane];
        float4 vv = reinterpret_cast<const float4*>(rv)[lane];
        o.x = di * elu_f((o.x + bb.x - mm.x) * rsqrtf(vv.x + EPSF) * gg.x + ee.x);
        o.y = di * elu_f((o.y + bb.y - mm.y) * rsqrtf(vv.y + EPSF) * gg.y + ee.y);
        o.z = di * elu_f((o.z + bb.z - mm.z) * rsqrtf(vv.z + EPSF) * gg.z + ee.z);
        o.w = di * elu_f((o.w + bb.w - mm.w) * rsqrtf(vv.w + EPSF) * gg.w + ee.w);
    }
    if (HOUT) reinterpret_cast<uint2*>(out)[(long)i * C + lane] = f4_to_h4(o);
    else      reinterpret_cast<float4*>(out)[(long)i * C + lane] = o;
}

// scalar gather for layer 4 (y pre-scaled by dinv) + bias + sigmoid(elu(.)) -> d_out
__global__ __launch_bounds__(256) void k_gather1_final(const int* __restrict__ base, const int* __restrict__ cnt,
                                                       const int* __restrict__ csr_s,
                                                       const float* __restrict__ dinv, const float* __restrict__ y,
                                                       const float* __restrict__ b4, float* __restrict__ out, int n) {
    int i = blockIdx.x * 256 + threadIdx.x;
    if (i >= n) return;
    int k = base[i];
    int kend = k + cnt[i];
    float di = dinv[i];
    float acc = 0.f;
    for (; k < kend; ++k) acc += y[csr_s[k]];
    float v = di * (acc + y[i]) + b4[0];
    v = elu_f(v);
    out[i] = 1.f / (1.f + expf(-v));
}

// ---------------- register-tiled dense GEMM ----------------
// Thread: TR=4 rows x 4 fouts. W staged in LDS. __launch_bounds__(256,4) caps VGPR (R3 lesson).
// SCALE_DINV: pre-scale output by dinv[row]. HOUT: write fp16 rows.
template<int DIN, int DOUT, bool BN, bool FUSE_DOT, bool SCALE_DINV, bool HOUT>
__global__ __launch_bounds__(256, 4) void k_gemm_rt(const float* __restrict__ X, const float* __restrict__ W,
                                                    const float* __restrict__ b, const float* __restrict__ g,
                                                    const float* __restrict__ be, const float* __restrict__ rm,
                                                    const float* __restrict__ rv, const float* __restrict__ W4,
                                                    const float* __restrict__ dinv,
                                                    void* __restrict__ Y, int n) {
    constexpr int TR = 4;
    constexpr int FL = DOUT / 4;       // fout-lane groups
    constexpr int RG = 256 / FL;       // row-groups per block
    constexpr int BR = RG * TR;        // rows per block
    __shared__ float Wl[DIN * DOUT];
    for (int idx = threadIdx.x; idx < DIN * DOUT; idx += 256) Wl[idx] = W[idx];
    __syncthreads();
    const int fl = threadIdx.x % FL;
    const int rg = threadIdx.x / FL;
    const int f0 = fl * 4;
    const long r0 = (long)blockIdx.x * BR + (long)rg * TR;

    float4 z; z.x = z.y = z.z = z.w = 0.f;
    float4 acc[TR];
    #pragma unroll
    for (int r = 0; r < TR; ++r) acc[r] = z;

    #pragma unroll 2
    for (int k0 = 0; k0 < DIN; k0 += 4) {
        float4 xv[TR];
        #pragma unroll
        for (int r = 0; r < TR; ++r) {
            long row = r0 + r;
            xv[r] = (row < n) ? *reinterpret_cast<const float4*>(X + row * DIN + k0) : z;
        }
        #pragma unroll
        for (int kk = 0; kk < 4; ++kk) {
            float4 w4 = *reinterpret_cast<const float4*>(&Wl[(k0 + kk) * DOUT + f0]);
            #pragma unroll
            for (int r = 0; r < TR; ++r) {
                float xs = (kk == 0) ? xv[r].x : (kk == 1) ? xv[r].y : (kk == 2) ? xv[r].z : xv[r].w;
                acc[r].x += xs * w4.x;
                acc[r].y += xs * w4.y;
                acc[r].z += xs * w4.z;
                acc[r].w += xs * w4.w;
            }
        }
    }

    float4 bias = z, scale = z, shift = z, w4d = z;
    if (BN) {
        bias = *reinterpret_cast<const float4*>(b + f0);
        float4 gg = *reinterpret_cast<const float4*>(g + f0);
        float4 ee = *reinterpret_cast<const float4*>(be + f0);
        float4 mm = *reinterpret_cast<const float4*>(rm + f0);
        float4 vv = *reinterpret_cast<const float4*>(rv + f0);
        scale.x = gg.x * rsqrtf(vv.x + EPSF); shift.x = ee.x - mm.x * scale.x;
        scale.y = gg.y * rsqrtf(vv.y + EPSF); shift.y = ee.y - mm.y * scale.y;
        scale.z = gg.z * rsqrtf(vv.z + EPSF); shift.z = ee.z - mm.z * scale.z;
        scale.w = gg.w * rsqrtf(vv.w + EPSF); shift.w = ee.w - mm.w * scale.w;
    }
    if (FUSE_DOT) w4d = *reinterpret_cast<const float4*>(W4 + f0);

    #pragma unroll
    for (int r = 0; r < TR; ++r) {
        long row = r0 + r;
        if (row >= n) continue;
        float4 v = acc[r];
        if (BN) {
            v.x = elu_f((v.x + bias.x) * scale.x + shift.x);
            v.y = elu_f((v.y + bias.y) * scale.y + shift.y);
            v.z = elu_f((v.z + bias.z) * scale.z + shift.z);
            v.w = elu_f((v.w + bias.w) * scale.w + shift.w);
        }
        float dv = SCALE_DINV ? dinv[row] : 1.f;
        if (FUSE_DOT) {
            float p = v.x * w4d.x + v.y * w4d.y + v.z * w4d.z + v.w * w4d.w;
            #pragma unroll
            for (int m = 1; m < FL; m <<= 1) p += __shfl_xor(p, m, 64);
            if (fl == 0) reinterpret_cast<float*>(Y)[row] = dv * p;
        } else {
            if (SCALE_DINV) { v.x *= dv; v.y *= dv; v.z *= dv; v.w *= dv; }
            if (HOUT) reinterpret_cast<uint2*>(Y)[row * FL + fl] = f4_to_h4(v);
            else      *reinterpret_cast<float4*>(reinterpret_cast<float*>(Y) + row * DOUT + f0) = v;
        }
    }
}

// ---------------- launch ----------------

extern "C" void kernel_launch(void* const* d_in, const int* in_sizes, int n_in,
                              void* d_out, int out_size, void* d_ws, size_t ws_size,
                              hipStream_t stream) {
    const float* x   = (const float*)d_in[0];
    const int*   edg = (const int*)d_in[1];
    const float* W1 = (const float*)d_in[2];
    const float* b1 = (const float*)d_in[3];
    const float* W2 = (const float*)d_in[4];
    const float* b2 = (const float*)d_in[5];
    const float* W3 = (const float*)d_in[6];
    const float* b3 = (const float*)d_in[7];
    const float* W4 = (const float*)d_in[8];
    const float* b4 = (const float*)d_in[9];
    const float* g1  = (const float*)d_in[10];
    const float* be1 = (const float*)d_in[11];
    const float* rm1 = (const float*)d_in[12];
    const float* rv1 = (const float*)d_in[13];
    const float* g2  = (const float*)d_in[14];
    const float* be2 = (const float*)d_in[15];
    const float* rm2 = (const float*)d_in[16];
    const float* rv2 = (const float*)d_in[17];
    const float* g3  = (const float*)d_in[18];
    const float* be3 = (const float*)d_in[19];
    const float* rm3 = (const float*)d_in[20];
    const float* rv3 = (const float*)d_in[21];
    float* out = (float*)d_out;

    const int N = in_sizes[0] / 64;
    const int E = in_sizes[1] / 2;
    const int* src = edg;
    const int* dst = edg + E;
    const int NB_BKT = (N + BKT_NODES - 1) / BKT_NODES;   // 196 for N=100000 (<=256)
    const int NTILES = (E + TILE_E - 1) / TILE_E;

    // workspace layout
    int*   bkt_cnt = (int*)d_ws;                    // 256
    int*   bbase   = bkt_cnt + 256;                 // 256
    int*   cursor  = bbase + 256;                   // 256
    int*   cnt     = cursor + 256;                  // N
    int*   base    = cnt + N;                       // N
    float* dinv    = (float*)(base + N);            // N
    int*   csr_s   = (int*)(dinv + N);              // E (permanent: gathers read it)
    float* featA   = (float*)(csr_s + E);           // N*64 f32 capacity
    float* featB   = featA + (size_t)N * 64;        // N*64 f32 capacity
    // alias lives only during CSR build (dead before featA is written):
    int2*  csr_tmp = (int2*)featA;                  // E int2 (12.8MB <= 25.6MB)

    auto nb = [](long total) { return (int)((total + 255) / 256); };

    // bucketed CSR build (per call: workspace re-poisoned every launch)
    k_zero<<<1, 256, 0, stream>>>(bkt_cnt, 256);
    k_bhist<<<512, 256, 0, stream>>>(dst, bkt_cnt, E);
    k_bscan<<<1, 256, 0, stream>>>(bkt_cnt, bbase, cursor);
    k_bpart<<<NTILES, 256, 0, stream>>>(src, dst, cursor, csr_tmp, E);
    k_bfine<<<NB_BKT, 256, 0, stream>>>(csr_tmp, bbase, bkt_cnt, cnt, base, dinv, csr_s, N);

    // Layer 1 (64->32): GEMM -> P1 fp16 (prescaled); gather+BN+ELU -> Q1 fp16 (prescaled)
    k_gemm_rt<64, 32, false, false, true, true><<<(N + 127) / 128, 256, 0, stream>>>(
        x, W1, nullptr, nullptr, nullptr, nullptr, nullptr, nullptr, dinv, featB, N);
    k_gather<32, true, true, true><<<(N + 31) / 32, 256, 0, stream>>>(base, cnt, csr_s, dinv, featB,
                                                                      b1, g1, be1, rm1, rv1, featA, N);

    // Layer 2 (32->64): gather Q1 fp16 -> T2 f32; GEMM+BN+ELU -> P2 fp16 (prescaled)
    k_gather<32, false, true, false><<<(N + 31) / 32, 256, 0, stream>>>(base, cnt, csr_s, dinv, featA,
                                                                        nullptr, nullptr, nullptr, nullptr, nullptr,
                                                                        featB, N);
    k_gemm_rt<32, 64, true, false, true, true><<<(N + 63) / 64, 256, 0, stream>>>(
        featB, W2, b2, g2, be2, rm2, rv2, nullptr, dinv, featA, N);

    // Layer 3 (64->128): gather P2 fp16 -> T3 f32; GEMM+BN+ELU+dot(W4) (prescaled) -> y f32
    k_gather<64, false, true, false><<<(N + 15) / 16, 256, 0, stream>>>(base, cnt, csr_s, dinv, featA,
                                                                        nullptr, nullptr, nullptr, nullptr, nullptr,
                                                                        featB, N);
    k_gemm_rt<64, 128, true, true, true, false><<<(N + 31) / 32, 256, 0, stream>>>(
        featB, W3, b3, g3, be3, rm3, rv3, W4, dinv, featA, N);

    // Layer 4 (128->1): scalar gather + bias + sigmoid(elu(.)) -> d_out
    k_gather1_final<<<nb(N), 256, 0, stream>>>(base, cnt, csr_s, dinv, featA, b4, out, N);
}

// Round 11
// 357.519 us; speedup vs baseline: 1.4278x; 1.0238x over previous
//
#include <hip/hip_runtime.h>
#include <hip/hip_fp16.h>

#define EPSF 1e-5f
#define BKT_SHIFT 9
#define BKT_NODES 512              // nodes per bucket
#define TILE_E 4096                // edges per k_bpart block

typedef _Float16 half2_t __attribute__((ext_vector_type(2)));

__device__ __forceinline__ float elu_f(float x) { return x > 0.f ? x : expm1f(x); }

// v_dot2_f32_f16: 2 fp16 MACs, f32 accumulate
__device__ __forceinline__ float fdot2f(half2_t a, half2_t b, float c) {
#if __has_builtin(__builtin_amdgcn_fdot2)
    return __builtin_amdgcn_fdot2(a, b, c, false);
#else
    return c + (float)a.x * (float)b.x + (float)a.y * (float)b.y;
#endif
}

// 4 halves <-> float4 (single 8B load/store on the fp16 side, f32 accumulation)
__device__ __forceinline__ float4 h4_to_f4(uint2 u) {
    __half2 a = *reinterpret_cast<const __half2*>(&u.x);
    __half2 b = *reinterpret_cast<const __half2*>(&u.y);
    float2 fa = __half22float2(a);
    float2 fb = __half22float2(b);
    return make_float4(fa.x, fa.y, fb.x, fb.y);
}
__device__ __forceinline__ uint2 f4_to_h4(float4 v) {
    __half2 a = __floats2half2_rn(v.x, v.y);
    __half2 b = __floats2half2_rn(v.z, v.w);
    uint2 u;
    u.x = *reinterpret_cast<unsigned*>(&a);
    u.y = *reinterpret_cast<unsigned*>(&b);
    return u;
}

// ---------------- bucketed CSR build ----------------

__global__ __launch_bounds__(256) void k_zero(int* p, int n) {
    int i = blockIdx.x * 256 + threadIdx.x;
    if (i < n) p[i] = 0;
}

__global__ __launch_bounds__(256) void k_bhist(const int* __restrict__ dst, int* __restrict__ bkt_cnt, int E) {
    __shared__ int h[256];
    int t = threadIdx.x;
    h[t] = 0;
    __syncthreads();
    for (long e = (long)blockIdx.x * 256 + t; e < E; e += (long)gridDim.x * 256)
        atomicAdd(&h[dst[e] >> BKT_SHIFT], 1);
    __syncthreads();
    if (h[t]) atomicAdd(&bkt_cnt[t], h[t]);
}

__global__ __launch_bounds__(256) void k_bscan(const int* __restrict__ bkt_cnt, int* __restrict__ bbase,
                                               int* __restrict__ cursor) {
    __shared__ int sh[256];
    int t = threadIdx.x;
    int v = bkt_cnt[t];
    sh[t] = v;
    __syncthreads();
    for (int off = 1; off < 256; off <<= 1) {
        int add = (t >= off) ? sh[t - off] : 0;
        __syncthreads();
        sh[t] += add;
        __syncthreads();
    }
    int ex = sh[t] - v;
    bbase[t] = ex;
    cursor[t] = ex;
}

__global__ __launch_bounds__(256) void k_bpart(const int* __restrict__ src, const int* __restrict__ dst,
                                               int* __restrict__ cursor, int2* __restrict__ csr_tmp, int E) {
    __shared__ int hcnt[256];
    __shared__ int gbase[256];
    int t = threadIdx.x;
    long tile0 = (long)blockIdx.x * TILE_E;
    hcnt[t] = 0;
    __syncthreads();
    int d[16], s[16], rk[16];
    #pragma unroll
    for (int j = 0; j < 16; ++j) {
        long e = tile0 + j * 256 + t;
        if (e < E) {
            d[j] = dst[e];
            s[j] = src[e];
            rk[j] = atomicAdd(&hcnt[d[j] >> BKT_SHIFT], 1);
        }
    }
    __syncthreads();
    int c = hcnt[t];
    if (c) gbase[t] = atomicAdd(&cursor[t], c);
    __syncthreads();
    #pragma unroll
    for (int j = 0; j < 16; ++j) {
        long e = tile0 + j * 256 + t;
        if (e < E) {
            int2 q;
            q.x = d[j];
            q.y = s[j];
            csr_tmp[gbase[d[j] >> BKT_SHIFT] + rk[j]] = q;
        }
    }
}

__global__ __launch_bounds__(256) void k_bfine(const int2* __restrict__ csr_tmp, const int* __restrict__ bbase,
                                               const int* __restrict__ bkt_cnt, int* __restrict__ cnt,
                                               int* __restrict__ base, float* __restrict__ dinv,
                                               int* __restrict__ csr_s, int N) {
    __shared__ int cnt5[BKT_NODES];
    __shared__ int off5[BKT_NODES];
    __shared__ int sh[256];
    int b = blockIdx.x;
    int t = threadIdx.x;
    int d0 = b << BKT_SHIFT;
    int bb = bbase[b];
    int bc = bkt_cnt[b];
    cnt5[t] = 0;
    cnt5[t + 256] = 0;
    __syncthreads();
    for (int k = t; k < bc; k += 256) atomicAdd(&cnt5[csr_tmp[bb + k].x - d0], 1);
    __syncthreads();
    int v0 = cnt5[2 * t], v1 = cnt5[2 * t + 1];
    int p = v0 + v1;
    sh[t] = p;
    __syncthreads();
    for (int off = 1; off < 256; off <<= 1) {
        int add = (t >= off) ? sh[t - off] : 0;
        __syncthreads();
        sh[t] += add;
        __syncthreads();
    }
    int pre = sh[t] - p;
    off5[2 * t] = pre;
    off5[2 * t + 1] = pre + v0;
    #pragma unroll
    for (int j = 0; j < 2; ++j) {
        int idx = 2 * t + j;
        int i = d0 + idx;
        if (i < N) {
            int c = cnt5[idx];
            base[i] = bb + off5[idx];
            cnt[i] = c;
            dinv[i] = rsqrtf((float)(c + 1));  // +1 self-loop
        }
    }
    __syncthreads();
    for (int k = t; k < bc; k += 256) {
        int2 e = csr_tmp[bb + k];
        int pos = bb + atomicAdd(&off5[e.x - d0], 1);
        csr_s[pos] = e.y;
    }
}

// ---------------- CSR gather-aggregate (weightless: features pre-scaled by dinv) ----------------
template<int F, bool L1EPI, bool HIN, bool HOUT>
__global__ __launch_bounds__(256) void k_gather(const int* __restrict__ base, const int* __restrict__ cnt,
                                                const int* __restrict__ csr_s,
                                                const float* __restrict__ dinv, const void* __restrict__ xin,
                                                const float* __restrict__ b, const float* __restrict__ g,
                                                const float* __restrict__ be, const float* __restrict__ rm,
                                                const float* __restrict__ rv, void* __restrict__ out, int n) {
    constexpr int C = F / 4;
    constexpr int NPB = 256 / C;
    int lane = threadIdx.x % C;
    int nl = threadIdx.x / C;
    int i = blockIdx.x * NPB + nl;
    if (i >= n) return;
    int k = base[i];
    int kend = k + cnt[i];
    float di = dinv[i];
    const float4* XF = reinterpret_cast<const float4*>(xin);
    const uint2*  XH = reinterpret_cast<const uint2*>(xin);
    float4 z = {0.f, 0.f, 0.f, 0.f};
    float4 a0 = z, a1 = z, a2 = z, a3 = z;
    for (; k + 3 < kend; k += 4) {
        int s0 = csr_s[k], s1 = csr_s[k + 1], s2 = csr_s[k + 2], s3 = csr_s[k + 3];
        float4 x0 = HIN ? h4_to_f4(XH[(long)s0 * C + lane]) : XF[(long)s0 * C + lane];
        float4 x1 = HIN ? h4_to_f4(XH[(long)s1 * C + lane]) : XF[(long)s1 * C + lane];
        float4 x2 = HIN ? h4_to_f4(XH[(long)s2 * C + lane]) : XF[(long)s2 * C + lane];
        float4 x3 = HIN ? h4_to_f4(XH[(long)s3 * C + lane]) : XF[(long)s3 * C + lane];
        a0.x += x0.x; a0.y += x0.y; a0.z += x0.z; a0.w += x0.w;
        a1.x += x1.x; a1.y += x1.y; a1.z += x1.z; a1.w += x1.w;
        a2.x += x2.x; a2.y += x2.y; a2.z += x2.z; a2.w += x2.w;
        a3.x += x3.x; a3.y += x3.y; a3.z += x3.z; a3.w += x3.w;
    }
    for (; k < kend; ++k) {
        int s0 = csr_s[k];
        float4 xa = HIN ? h4_to_f4(XH[(long)s0 * C + lane]) : XF[(long)s0 * C + lane];
        a0.x += xa.x; a0.y += xa.y; a0.z += xa.z; a0.w += xa.w;
    }
    float4 xs = HIN ? h4_to_f4(XH[(long)i * C + lane]) : XF[(long)i * C + lane];
    float4 o;
    o.x = di * (a0.x + a1.x + a2.x + a3.x + xs.x);
    o.y = di * (a0.y + a1.y + a2.y + a3.y + xs.y);
    o.z = di * (a0.z + a1.z + a2.z + a3.z + xs.z);
    o.w = di * (a0.w + a1.w + a2.w + a3.w + xs.w);
    if (L1EPI) {
        float4 bb = reinterpret_cast<const float4*>(b)[lane];
        float4 gg = reinterpret_cast<const float4*>(g)[lane];
        float4 ee = reinterpret_cast<const float4*>(be)[lane];
        float4 mm = reinterpret_cast<const float4*>(rm)[lane];
        float4 vv = reinterpret_cast<const float4*>(rv)[lane];
        o.x = di * elu_f((o.x + bb.x - mm.x) * rsqrtf(vv.x + EPSF) * gg.x + ee.x);
        o.y = di * elu_f((o.y + bb.y - mm.y) * rsqrtf(vv.y + EPSF) * gg.y + ee.y);
        o.z = di * elu_f((o.z + bb.z - mm.z) * rsqrtf(vv.z + EPSF) * gg.z + ee.z);
        o.w = di * elu_f((o.w + bb.w - mm.w) * rsqrtf(vv.w + EPSF) * gg.w + ee.w);
    }
    if (HOUT) reinterpret_cast<uint2*>(out)[(long)i * C + lane] = f4_to_h4(o);
    else      reinterpret_cast<float4*>(out)[(long)i * C + lane] = o;
}

// scalar gather for layer 4 (y pre-scaled by dinv) + bias + sigmoid(elu(.)) -> d_out
__global__ __launch_bounds__(256) void k_gather1_final(const int* __restrict__ base, const int* __restrict__ cnt,
                                                       const int* __restrict__ csr_s,
                                                       const float* __restrict__ dinv, const float* __restrict__ y,
                                                       const float* __restrict__ b4, float* __restrict__ out, int n) {
    int i = blockIdx.x * 256 + threadIdx.x;
    if (i >= n) return;
    int k = base[i];
    int kend = k + cnt[i];
    float di = dinv[i];
    float acc = 0.f;
    for (; k < kend; ++k) acc += y[csr_s[k]];
    float v = di * (acc + y[i]) + b4[0];
    v = elu_f(v);
    out[i] = 1.f / (1.f + expf(-v));
}

// ---------------- f32 register-tiled GEMM (layer 1: f32 x input) ----------------
template<int DIN, int DOUT, bool BN, bool FUSE_DOT, bool SCALE_DINV, bool HOUT>
__global__ __launch_bounds__(256, 4) void k_gemm_rt(const float* __restrict__ X, const float* __restrict__ W,
                                                    const float* __restrict__ b, const float* __restrict__ g,
                                                    const float* __restrict__ be, const float* __restrict__ rm,
                                                    const float* __restrict__ rv, const float* __restrict__ W4,
                                                    const float* __restrict__ dinv,
                                                    void* __restrict__ Y, int n) {
    constexpr int TR = 4;
    constexpr int FL = DOUT / 4;
    constexpr int RG = 256 / FL;
    constexpr int BR = RG * TR;
    __shared__ float Wl[DIN * DOUT];
    for (int idx = threadIdx.x; idx < DIN * DOUT; idx += 256) Wl[idx] = W[idx];
    __syncthreads();
    const int fl = threadIdx.x % FL;
    const int rg = threadIdx.x / FL;
    const int f0 = fl * 4;
    const long r0 = (long)blockIdx.x * BR + (long)rg * TR;

    float4 z; z.x = z.y = z.z = z.w = 0.f;
    float4 acc[TR];
    #pragma unroll
    for (int r = 0; r < TR; ++r) acc[r] = z;

    #pragma unroll 2
    for (int k0 = 0; k0 < DIN; k0 += 4) {
        float4 xv[TR];
        #pragma unroll
        for (int r = 0; r < TR; ++r) {
            long row = r0 + r;
            xv[r] = (row < n) ? *reinterpret_cast<const float4*>(X + row * DIN + k0) : z;
        }
        #pragma unroll
        for (int kk = 0; kk < 4; ++kk) {
            float4 w4 = *reinterpret_cast<const float4*>(&Wl[(k0 + kk) * DOUT + f0]);
            #pragma unroll
            for (int r = 0; r < TR; ++r) {
                float xs = (kk == 0) ? xv[r].x : (kk == 1) ? xv[r].y : (kk == 2) ? xv[r].z : xv[r].w;
                acc[r].x += xs * w4.x;
                acc[r].y += xs * w4.y;
                acc[r].z += xs * w4.z;
                acc[r].w += xs * w4.w;
            }
        }
    }

    float4 bias = z, scale = z, shift = z, w4d = z;
    if (BN) {
        bias = *reinterpret_cast<const float4*>(b + f0);
        float4 gg = *reinterpret_cast<const float4*>(g + f0);
        float4 ee = *reinterpret_cast<const float4*>(be + f0);
        float4 mm = *reinterpret_cast<const float4*>(rm + f0);
        float4 vv = *reinterpret_cast<const float4*>(rv + f0);
        scale.x = gg.x * rsqrtf(vv.x + EPSF); shift.x = ee.x - mm.x * scale.x;
        scale.y = gg.y * rsqrtf(vv.y + EPSF); shift.y = ee.y - mm.y * scale.y;
        scale.z = gg.z * rsqrtf(vv.z + EPSF); shift.z = ee.z - mm.z * scale.z;
        scale.w = gg.w * rsqrtf(vv.w + EPSF); shift.w = ee.w - mm.w * scale.w;
    }
    if (FUSE_DOT) w4d = *reinterpret_cast<const float4*>(W4 + f0);

    #pragma unroll
    for (int r = 0; r < TR; ++r) {
        long row = r0 + r;
        if (row >= n) continue;
        float4 v = acc[r];
        if (BN) {
            v.x = elu_f((v.x + bias.x) * scale.x + shift.x);
            v.y = elu_f((v.y + bias.y) * scale.y + shift.y);
            v.z = elu_f((v.z + bias.z) * scale.z + shift.z);
            v.w = elu_f((v.w + bias.w) * scale.w + shift.w);
        }
        float dv = SCALE_DINV ? dinv[row] : 1.f;
        if (FUSE_DOT) {
            float p = v.x * w4d.x + v.y * w4d.y + v.z * w4d.z + v.w * w4d.w;
            #pragma unroll
            for (int m = 1; m < FL; m <<= 1) p += __shfl_xor(p, m, 64);
            if (fl == 0) reinterpret_cast<float*>(Y)[row] = dv * p;
        } else {
            if (SCALE_DINV) { v.x *= dv; v.y *= dv; v.z *= dv; v.w *= dv; }
            if (HOUT) reinterpret_cast<uint2*>(Y)[row * FL + fl] = f4_to_h4(v);
            else      *reinterpret_cast<float4*>(reinterpret_cast<float*>(Y) + row * DOUT + f0) = v;
        }
    }
}

// ---------------- fp16 register-tiled GEMM via v_dot2_f32_f16 (layers 2,3) ----------------
// X rows fp16 (uint4 = 8 halves), W converted to half2 in LDS (k-pair-major [DIN/2][DOUT]):
// same 16B-contiguous ds_read_b128 pattern as the f32 kernel (0 bank conflicts observed)
// at half the read count; FMA instruction count halved via dot2; f32 accumulation.
template<int DIN, int DOUT, bool BN, bool FUSE_DOT, bool SCALE_DINV, bool HOUT>
__global__ __launch_bounds__(256, 4) void k_gemm_h(const uint4* __restrict__ Xh, const float* __restrict__ W,
                                                   const float* __restrict__ b, const float* __restrict__ g,
                                                   const float* __restrict__ be, const float* __restrict__ rm,
                                                   const float* __restrict__ rv, const float* __restrict__ W4,
                                                   const float* __restrict__ dinv,
                                                   void* __restrict__ Y, int n) {
    constexpr int TR = 4;
    constexpr int FL = DOUT / 4;       // fout-lane groups (4 fouts/thread)
    constexpr int RG = 256 / FL;
    constexpr int BR = RG * TR;
    constexpr int PK = DIN / 2;        // k-pairs
    constexpr int XW = DIN / 8;        // uint4 per row
    __shared__ half2_t Wl2[PK * DOUT];
    for (int idx = threadIdx.x; idx < PK * DOUT; idx += 256) {
        int p = idx / DOUT, j = idx % DOUT;
        half2_t w;
        w.x = (_Float16)W[(2 * p) * DOUT + j];
        w.y = (_Float16)W[(2 * p + 1) * DOUT + j];
        Wl2[idx] = w;
    }
    __syncthreads();
    const int fl = threadIdx.x % FL;
    const int rg = threadIdx.x / FL;
    const int f0 = fl * 4;
    const long r0 = (long)blockIdx.x * BR + (long)rg * TR;

    float4 z; z.x = z.y = z.z = z.w = 0.f;
    float4 acc[TR];
    #pragma unroll
    for (int r = 0; r < TR; ++r) acc[r] = z;
    uint4 uz = {0u, 0u, 0u, 0u};

    #pragma unroll 2
    for (int k0 = 0; k0 < DIN; k0 += 8) {
        uint4 xv[TR];
        #pragma unroll
        for (int r = 0; r < TR; ++r) {
            long row = r0 + r;
            xv[r] = (row < n) ? Xh[row * XW + (k0 >> 3)] : uz;
        }
        #pragma unroll
        for (int p = 0; p < 4; ++p) {   // k-pair = k0/2 + p
            uint4 wv = *reinterpret_cast<const uint4*>(&Wl2[(size_t)((k0 >> 1) + p) * DOUT + f0]);
            half2_t w0 = __builtin_bit_cast(half2_t, wv.x);
            half2_t w1 = __builtin_bit_cast(half2_t, wv.y);
            half2_t w2h = __builtin_bit_cast(half2_t, wv.z);
            half2_t w3h = __builtin_bit_cast(half2_t, wv.w);
            #pragma unroll
            for (int r = 0; r < TR; ++r) {
                unsigned xu = (p == 0) ? xv[r].x : (p == 1) ? xv[r].y : (p == 2) ? xv[r].z : xv[r].w;
                half2_t xp = __builtin_bit_cast(half2_t, xu);
                acc[r].x = fdot2f(xp, w0, acc[r].x);
                acc[r].y = fdot2f(xp, w1, acc[r].y);
                acc[r].z = fdot2f(xp, w2h, acc[r].z);
                acc[r].w = fdot2f(xp, w3h, acc[r].w);
            }
        }
    }

    float4 bias = z, scale = z, shift = z, w4d = z;
    if (BN) {
        bias = *reinterpret_cast<const float4*>(b + f0);
        float4 gg = *reinterpret_cast<const float4*>(g + f0);
        float4 ee = *reinterpret_cast<const float4*>(be + f0);
        float4 mm = *reinterpret_cast<const float4*>(rm + f0);
        float4 vv = *reinterpret_cast<const float4*>(rv + f0);
        scale.x = gg.x * rsqrtf(vv.x + EPSF); shift.x = ee.x - mm.x * scale.x;
        scale.y = gg.y * rsqrtf(vv.y + EPSF); shift.y = ee.y - mm.y * scale.y;
        scale.z = gg.z * rsqrtf(vv.z + EPSF); shift.z = ee.z - mm.z * scale.z;
        scale.w = gg.w * rsqrtf(vv.w + EPSF); shift.w = ee.w - mm.w * scale.w;
    }
    if (FUSE_DOT) w4d = *reinterpret_cast<const float4*>(W4 + f0);

    #pragma unroll
    for (int r = 0; r < TR; ++r) {
        long row = r0 + r;
        if (row >= n) continue;
        float4 v = acc[r];
        if (BN) {
            v.x = elu_f((v.x + bias.x) * scale.x + shift.x);
            v.y = elu_f((v.y + bias.y) * scale.y + shift.y);
            v.z = elu_f((v.z + bias.z) * scale.z + shift.z);
            v.w = elu_f((v.w + bias.w) * scale.w + shift.w);
        }
        float dv = SCALE_DINV ? dinv[row] : 1.f;
        if (FUSE_DOT) {
            float p = v.x * w4d.x + v.y * w4d.y + v.z * w4d.z + v.w * w4d.w;
            #pragma unroll
            for (int m = 1; m < FL; m <<= 1) p += __shfl_xor(p, m, 64);
            if (fl == 0) reinterpret_cast<float*>(Y)[row] = dv * p;
        } else {
            if (SCALE_DINV) { v.x *= dv; v.y *= dv; v.z *= dv; v.w *= dv; }
            if (HOUT) reinterpret_cast<uint2*>(Y)[row * FL + fl] = f4_to_h4(v);
            else      *reinterpret_cast<float4*>(reinterpret_cast<float*>(Y) + row * DOUT + f0) = v;
        }
    }
}

// ---------------- launch ----------------

extern "C" void kernel_launch(void* const* d_in, const int* in_sizes, int n_in,
                              void* d_out, int out_size, void* d_ws, size_t ws_size,
                              hipStream_t stream) {
    const float* x   = (const float*)d_in[0];
    const int*   edg = (const int*)d_in[1];
    const float* W1 = (const float*)d_in[2];
    const float* b1 = (const float*)d_in[3];
    const float* W2 = (const float*)d_in[4];
    const float* b2 = (const float*)d_in[5];
    const float* W3 = (const float*)d_in[6];
    const float* b3 = (const float*)d_in[7];
    const float* W4 = (const float*)d_in[8];
    const float* b4 = (const float*)d_in[9];
    const float* g1  = (const float*)d_in[10];
    const float* be1 = (const float*)d_in[11];
    const float* rm1 = (const float*)d_in[12];
    const float* rv1 = (const float*)d_in[13];
    const float* g2  = (const float*)d_in[14];
    const float* be2 = (const float*)d_in[15];
    const float* rm2 = (const float*)d_in[16];
    const float* rv2 = (const float*)d_in[17];
    const float* g3  = (const float*)d_in[18];
    const float* be3 = (const float*)d_in[19];
    const float* rm3 = (const float*)d_in[20];
    const float* rv3 = (const float*)d_in[21];
    float* out = (float*)d_out;

    const int N = in_sizes[0] / 64;
    const int E = in_sizes[1] / 2;
    const int* src = edg;
    const int* dst = edg + E;
    const int NB_BKT = (N + BKT_NODES - 1) / BKT_NODES;
    const int NTILES = (E + TILE_E - 1) / TILE_E;

    // workspace layout
    int*   bkt_cnt = (int*)d_ws;                    // 256
    int*   bbase   = bkt_cnt + 256;                 // 256
    int*   cursor  = bbase + 256;                   // 256
    int*   cnt     = cursor + 256;                  // N
    int*   base    = cnt + N;                       // N
    float* dinv    = (float*)(base + N);            // N
    int*   csr_s   = (int*)(dinv + N);              // E (permanent: gathers read it)
    float* featA   = (float*)(csr_s + E);           // N*64 f32 capacity
    float* featB   = featA + (size_t)N * 64;        // N*64 f32 capacity
    int2*  csr_tmp = (int2*)featA;                  // CSR-build-only alias

    auto nb = [](long total) { return (int)((total + 255) / 256); };

    // bucketed CSR build
    k_zero<<<1, 256, 0, stream>>>(bkt_cnt, 256);
    k_bhist<<<512, 256, 0, stream>>>(dst, bkt_cnt, E);
    k_bscan<<<1, 256, 0, stream>>>(bkt_cnt, bbase, cursor);
    k_bpart<<<NTILES, 256, 0, stream>>>(src, dst, cursor, csr_tmp, E);
    k_bfine<<<NB_BKT, 256, 0, stream>>>(csr_tmp, bbase, bkt_cnt, cnt, base, dinv, csr_s, N);

    // Layer 1 (64->32): f32 GEMM -> P1 fp16 (prescaled); gather+BN+ELU -> Q1 fp16 (prescaled)
    k_gemm_rt<64, 32, false, false, true, true><<<(N + 127) / 128, 256, 0, stream>>>(
        x, W1, nullptr, nullptr, nullptr, nullptr, nullptr, nullptr, dinv, featB, N);
    k_gather<32, true, true, true><<<(N + 31) / 32, 256, 0, stream>>>(base, cnt, csr_s, dinv, featB,
                                                                      b1, g1, be1, rm1, rv1, featA, N);

    // Layer 2 (32->64): gather Q1 -> T2 fp16; fp16 GEMM+BN+ELU -> P2 fp16 (prescaled)
    k_gather<32, false, true, true><<<(N + 31) / 32, 256, 0, stream>>>(base, cnt, csr_s, dinv, featA,
                                                                       nullptr, nullptr, nullptr, nullptr, nullptr,
                                                                       featB, N);
    k_gemm_h<32, 64, true, false, true, true><<<(N + 63) / 64, 256, 0, stream>>>(
        (const uint4*)featB, W2, b2, g2, be2, rm2, rv2, nullptr, dinv, featA, N);

    // Layer 3 (64->128): gather P2 -> T3 fp16; fp16 GEMM+BN+ELU+dot(W4) (prescaled) -> y f32
    k_gather<64, false, true, true><<<(N + 15) / 16, 256, 0, stream>>>(base, cnt, csr_s, dinv, featA,
                                                                       nullptr, nullptr, nullptr, nullptr, nullptr,
                                                                       featB, N);
    k_gemm_h<64, 128, true, true, true, false><<<(N + 31) / 32, 256, 0, stream>>>(
        (const uint4*)featB, W3, b3, g3, be3, rm3, rv3, W4, dinv, featA, N);

    // Layer 4 (128->1): scalar gather + bias + sigmoid(elu(.)) -> d_out
    k_gather1_final<<<nb(N), 256, 0, stream>>>(base, cnt, csr_s, dinv, featA, b4, out, N);
}

// Round 12
// 343.886 us; speedup vs baseline: 1.4844x; 1.0396x over previous
//
#include <hip/hip_runtime.h>
#include <hip/hip_fp16.h>

#define EPSF 1e-5f
#define BKT_SHIFT 9
#define BKT_NODES 512              // nodes per bucket
#define TILE_E 4096                // edges per k_bpart block

typedef _Float16 half2_t __attribute__((ext_vector_type(2)));

__device__ __forceinline__ float elu_f(float x) { return x > 0.f ? x : expm1f(x); }

// v_dot2_f32_f16: 2 fp16 MACs, f32 accumulate
__device__ __forceinline__ float fdot2f(half2_t a, half2_t b, float c) {
#if __has_builtin(__builtin_amdgcn_fdot2)
    return __builtin_amdgcn_fdot2(a, b, c, false);
#else
    return c + (float)a.x * (float)b.x + (float)a.y * (float)b.y;
#endif
}
__device__ __forceinline__ half2_t bch2(unsigned u) { return __builtin_bit_cast(half2_t, u); }

// 4 halves <-> float4 (f32 accumulation everywhere)
__device__ __forceinline__ float4 h4_to_f4(uint2 u) {
    __half2 a = *reinterpret_cast<const __half2*>(&u.x);
    __half2 b = *reinterpret_cast<const __half2*>(&u.y);
    float2 fa = __half22float2(a);
    float2 fb = __half22float2(b);
    return make_float4(fa.x, fa.y, fb.x, fb.y);
}
__device__ __forceinline__ uint2 f4_to_h4(float4 v) {
    __half2 a = __floats2half2_rn(v.x, v.y);
    __half2 b = __floats2half2_rn(v.z, v.w);
    uint2 u;
    u.x = *reinterpret_cast<unsigned*>(&a);
    u.y = *reinterpret_cast<unsigned*>(&b);
    return u;
}

// ---------------- bucketed CSR build ----------------

__global__ __launch_bounds__(256) void k_zero(int* p, int n) {
    int i = blockIdx.x * 256 + threadIdx.x;
    if (i < n) p[i] = 0;
}

__global__ __launch_bounds__(256) void k_bhist(const int* __restrict__ dst, int* __restrict__ bkt_cnt, int E) {
    __shared__ int h[256];
    int t = threadIdx.x;
    h[t] = 0;
    __syncthreads();
    for (long e = (long)blockIdx.x * 256 + t; e < E; e += (long)gridDim.x * 256)
        atomicAdd(&h[dst[e] >> BKT_SHIFT], 1);
    __syncthreads();
    if (h[t]) atomicAdd(&bkt_cnt[t], h[t]);
}

__global__ __launch_bounds__(256) void k_bscan(const int* __restrict__ bkt_cnt, int* __restrict__ bbase,
                                               int* __restrict__ cursor) {
    __shared__ int sh[256];
    int t = threadIdx.x;
    int v = bkt_cnt[t];
    sh[t] = v;
    __syncthreads();
    for (int off = 1; off < 256; off <<= 1) {
        int add = (t >= off) ? sh[t - off] : 0;
        __syncthreads();
        sh[t] += add;
        __syncthreads();
    }
    int ex = sh[t] - v;
    bbase[t] = ex;
    cursor[t] = ex;
}

__global__ __launch_bounds__(256) void k_bpart(const int* __restrict__ src, const int* __restrict__ dst,
                                               int* __restrict__ cursor, int2* __restrict__ csr_tmp, int E) {
    __shared__ int hcnt[256];
    __shared__ int gbase[256];
    int t = threadIdx.x;
    long tile0 = (long)blockIdx.x * TILE_E;
    hcnt[t] = 0;
    __syncthreads();
    int d[16], s[16], rk[16];
    #pragma unroll
    for (int j = 0; j < 16; ++j) {
        long e = tile0 + j * 256 + t;
        if (e < E) {
            d[j] = dst[e];
            s[j] = src[e];
            rk[j] = atomicAdd(&hcnt[d[j] >> BKT_SHIFT], 1);
        }
    }
    __syncthreads();
    int c = hcnt[t];
    if (c) gbase[t] = atomicAdd(&cursor[t], c);
    __syncthreads();
    #pragma unroll
    for (int j = 0; j < 16; ++j) {
        long e = tile0 + j * 256 + t;
        if (e < E) {
            int2 q;
            q.x = d[j];
            q.y = s[j];
            csr_tmp[gbase[d[j] >> BKT_SHIFT] + rk[j]] = q;
        }
    }
}

__global__ __launch_bounds__(256) void k_bfine(const int2* __restrict__ csr_tmp, const int* __restrict__ bbase,
                                               const int* __restrict__ bkt_cnt, int* __restrict__ cnt,
                                               int* __restrict__ base, float* __restrict__ dinv,
                                               int* __restrict__ csr_s, int N) {
    __shared__ int cnt5[BKT_NODES];
    __shared__ int off5[BKT_NODES];
    __shared__ int sh[256];
    int b = blockIdx.x;
    int t = threadIdx.x;
    int d0 = b << BKT_SHIFT;
    int bb = bbase[b];
    int bc = bkt_cnt[b];
    cnt5[t] = 0;
    cnt5[t + 256] = 0;
    __syncthreads();
    for (int k = t; k < bc; k += 256) atomicAdd(&cnt5[csr_tmp[bb + k].x - d0], 1);
    __syncthreads();
    int v0 = cnt5[2 * t], v1 = cnt5[2 * t + 1];
    int p = v0 + v1;
    sh[t] = p;
    __syncthreads();
    for (int off = 1; off < 256; off <<= 1) {
        int add = (t >= off) ? sh[t - off] : 0;
        __syncthreads();
        sh[t] += add;
        __syncthreads();
    }
    int pre = sh[t] - p;
    off5[2 * t] = pre;
    off5[2 * t + 1] = pre + v0;
    #pragma unroll
    for (int j = 0; j < 2; ++j) {
        int idx = 2 * t + j;
        int i = d0 + idx;
        if (i < N) {
            int c = cnt5[idx];
            base[i] = bb + off5[idx];
            cnt[i] = c;
            dinv[i] = rsqrtf((float)(c + 1));  // +1 self-loop
        }
    }
    __syncthreads();
    for (int k = t; k < bc; k += 256) {
        int2 e = csr_tmp[bb + k];
        int pos = bb + atomicAdd(&off5[e.x - d0], 1);
        csr_s[pos] = e.y;
    }
}

// ---------------- standalone gather (layer 1, fp16 in/out, BN+ELU epilogue) ----------------
template<int F, bool L1EPI, bool HIN, bool HOUT>
__global__ __launch_bounds__(256) void k_gather(const int* __restrict__ base, const int* __restrict__ cnt,
                                                const int* __restrict__ csr_s,
                                                const float* __restrict__ dinv, const void* __restrict__ xin,
                                                const float* __restrict__ b, const float* __restrict__ g,
                                                const float* __restrict__ be, const float* __restrict__ rm,
                                                const float* __restrict__ rv, void* __restrict__ out, int n) {
    constexpr int C = F / 4;
    constexpr int NPB = 256 / C;
    int lane = threadIdx.x % C;
    int nl = threadIdx.x / C;
    int i = blockIdx.x * NPB + nl;
    if (i >= n) return;
    int k = base[i];
    int kend = k + cnt[i];
    float di = dinv[i];
    const float4* XF = reinterpret_cast<const float4*>(xin);
    const uint2*  XH = reinterpret_cast<const uint2*>(xin);
    float4 z = {0.f, 0.f, 0.f, 0.f};
    float4 a0 = z, a1 = z, a2 = z, a3 = z;
    for (; k + 3 < kend; k += 4) {
        int s0 = csr_s[k], s1 = csr_s[k + 1], s2 = csr_s[k + 2], s3 = csr_s[k + 3];
        float4 x0 = HIN ? h4_to_f4(XH[(long)s0 * C + lane]) : XF[(long)s0 * C + lane];
        float4 x1 = HIN ? h4_to_f4(XH[(long)s1 * C + lane]) : XF[(long)s1 * C + lane];
        float4 x2 = HIN ? h4_to_f4(XH[(long)s2 * C + lane]) : XF[(long)s2 * C + lane];
        float4 x3 = HIN ? h4_to_f4(XH[(long)s3 * C + lane]) : XF[(long)s3 * C + lane];
        a0.x += x0.x; a0.y += x0.y; a0.z += x0.z; a0.w += x0.w;
        a1.x += x1.x; a1.y += x1.y; a1.z += x1.z; a1.w += x1.w;
        a2.x += x2.x; a2.y += x2.y; a2.z += x2.z; a2.w += x2.w;
        a3.x += x3.x; a3.y += x3.y; a3.z += x3.z; a3.w += x3.w;
    }
    for (; k < kend; ++k) {
        int s0 = csr_s[k];
        float4 xa = HIN ? h4_to_f4(XH[(long)s0 * C + lane]) : XF[(long)s0 * C + lane];
        a0.x += xa.x; a0.y += xa.y; a0.z += xa.z; a0.w += xa.w;
    }
    float4 xs = HIN ? h4_to_f4(XH[(long)i * C + lane]) : XF[(long)i * C + lane];
    float4 o;
    o.x = di * (a0.x + a1.x + a2.x + a3.x + xs.x);
    o.y = di * (a0.y + a1.y + a2.y + a3.y + xs.y);
    o.z = di * (a0.z + a1.z + a2.z + a3.z + xs.z);
    o.w = di * (a0.w + a1.w + a2.w + a3.w + xs.w);
    if (L1EPI) {
        float4 bb = reinterpret_cast<const float4*>(b)[lane];
        float4 gg = reinterpret_cast<const float4*>(g)[lane];
        float4 ee = reinterpret_cast<const float4*>(be)[lane];
        float4 mm = reinterpret_cast<const float4*>(rm)[lane];
        float4 vv = reinterpret_cast<const float4*>(rv)[lane];
        o.x = di * elu_f((o.x + bb.x - mm.x) * rsqrtf(vv.x + EPSF) * gg.x + ee.x);
        o.y = di * elu_f((o.y + bb.y - mm.y) * rsqrtf(vv.y + EPSF) * gg.y + ee.y);
        o.z = di * elu_f((o.z + bb.z - mm.z) * rsqrtf(vv.z + EPSF) * gg.z + ee.z);
        o.w = di * elu_f((o.w + bb.w - mm.w) * rsqrtf(vv.w + EPSF) * gg.w + ee.w);
    }
    if (HOUT) reinterpret_cast<uint2*>(out)[(long)i * C + lane] = f4_to_h4(o);
    else      reinterpret_cast<float4*>(out)[(long)i * C + lane] = o;
}

// scalar gather for layer 4 (y pre-scaled by dinv) + bias + sigmoid(elu(.)) -> d_out
__global__ __launch_bounds__(256) void k_gather1_final(const int* __restrict__ base, const int* __restrict__ cnt,
                                                       const int* __restrict__ csr_s,
                                                       const float* __restrict__ dinv, const float* __restrict__ y,
                                                       const float* __restrict__ b4, float* __restrict__ out, int n) {
    int i = blockIdx.x * 256 + threadIdx.x;
    if (i >= n) return;
    int k = base[i];
    int kend = k + cnt[i];
    float di = dinv[i];
    float acc = 0.f;
    for (; k < kend; ++k) acc += y[csr_s[k]];
    float v = di * (acc + y[i]) + b4[0];
    v = elu_f(v);
    out[i] = 1.f / (1.f + expf(-v));
}

// ---------------- f32 register-tiled GEMM (layer 1: f32 x input -> fp16 prescaled) ----------------
template<int DIN, int DOUT, bool BN, bool FUSE_DOT, bool SCALE_DINV, bool HOUT>
__global__ __launch_bounds__(256, 4) void k_gemm_rt(const float* __restrict__ X, const float* __restrict__ W,
                                                    const float* __restrict__ b, const float* __restrict__ g,
                                                    const float* __restrict__ be, const float* __restrict__ rm,
                                                    const float* __restrict__ rv, const float* __restrict__ W4,
                                                    const float* __restrict__ dinv,
                                                    void* __restrict__ Y, int n) {
    constexpr int TR = 4;
    constexpr int FL = DOUT / 4;
    constexpr int RG = 256 / FL;
    constexpr int BR = RG * TR;
    __shared__ float Wl[DIN * DOUT];
    for (int idx = threadIdx.x; idx < DIN * DOUT; idx += 256) Wl[idx] = W[idx];
    __syncthreads();
    const int fl = threadIdx.x % FL;
    const int rg = threadIdx.x / FL;
    const int f0 = fl * 4;
    const long r0 = (long)blockIdx.x * BR + (long)rg * TR;

    float4 z; z.x = z.y = z.z = z.w = 0.f;
    float4 acc[TR];
    #pragma unroll
    for (int r = 0; r < TR; ++r) acc[r] = z;

    #pragma unroll 2
    for (int k0 = 0; k0 < DIN; k0 += 4) {
        float4 xv[TR];
        #pragma unroll
        for (int r = 0; r < TR; ++r) {
            long row = r0 + r;
            xv[r] = (row < n) ? *reinterpret_cast<const float4*>(X + row * DIN + k0) : z;
        }
        #pragma unroll
        for (int kk = 0; kk < 4; ++kk) {
            float4 w4 = *reinterpret_cast<const float4*>(&Wl[(k0 + kk) * DOUT + f0]);
            #pragma unroll
            for (int r = 0; r < TR; ++r) {
                float xs = (kk == 0) ? xv[r].x : (kk == 1) ? xv[r].y : (kk == 2) ? xv[r].z : xv[r].w;
                acc[r].x += xs * w4.x;
                acc[r].y += xs * w4.y;
                acc[r].z += xs * w4.z;
                acc[r].w += xs * w4.w;
            }
        }
    }

    float4 bias = z, scale = z, shift = z, w4d = z;
    if (BN) {
        bias = *reinterpret_cast<const float4*>(b + f0);
        float4 gg = *reinterpret_cast<const float4*>(g + f0);
        float4 ee = *reinterpret_cast<const float4*>(be + f0);
        float4 mm = *reinterpret_cast<const float4*>(rm + f0);
        float4 vv = *reinterpret_cast<const float4*>(rv + f0);
        scale.x = gg.x * rsqrtf(vv.x + EPSF); shift.x = ee.x - mm.x * scale.x;
        scale.y = gg.y * rsqrtf(vv.y + EPSF); shift.y = ee.y - mm.y * scale.y;
        scale.z = gg.z * rsqrtf(vv.z + EPSF); shift.z = ee.z - mm.z * scale.z;
        scale.w = gg.w * rsqrtf(vv.w + EPSF); shift.w = ee.w - mm.w * scale.w;
    }
    if (FUSE_DOT) w4d = *reinterpret_cast<const float4*>(W4 + f0);

    #pragma unroll
    for (int r = 0; r < TR; ++r) {
        long row = r0 + r;
        if (row >= n) continue;
        float4 v = acc[r];
        if (BN) {
            v.x = elu_f((v.x + bias.x) * scale.x + shift.x);
            v.y = elu_f((v.y + bias.y) * scale.y + shift.y);
            v.z = elu_f((v.z + bias.z) * scale.z + shift.z);
            v.w = elu_f((v.w + bias.w) * scale.w + shift.w);
        }
        float dv = SCALE_DINV ? dinv[row] : 1.f;
        if (FUSE_DOT) {
            float p = v.x * w4d.x + v.y * w4d.y + v.z * w4d.z + v.w * w4d.w;
            #pragma unroll
            for (int m = 1; m < FL; m <<= 1) p += __shfl_xor(p, m, 64);
            if (fl == 0) reinterpret_cast<float*>(Y)[row] = dv * p;
        } else {
            if (SCALE_DINV) { v.x *= dv; v.y *= dv; v.z *= dv; v.w *= dv; }
            if (HOUT) reinterpret_cast<uint2*>(Y)[row * FL + fl] = f4_to_h4(v);
            else      *reinterpret_cast<float4*>(reinterpret_cast<float*>(Y) + row * DOUT + f0) = v;
        }
    }
}

// ---------------- fused gather + fp16 GEMM, layer 2 (32 -> 64) ----------------
// Block = 32 rows. Phase A: gather fp16 Q1 rows (f32 acc, x dinv), pack to LDS tile.
// Phase B: dot2 GEMM from LDS tile x W2(LDS half2) + BN + ELU + dinv prescale -> P2 fp16.
__global__ __launch_bounds__(256, 4) void k_fuse2(const int* __restrict__ base, const int* __restrict__ cnt,
                                                  const int* __restrict__ csr_s, const float* __restrict__ dinv,
                                                  const uint2* __restrict__ Xh,   // Q1: 8 uint2 per row
                                                  const float* __restrict__ W, const float* __restrict__ b,
                                                  const float* __restrict__ g, const float* __restrict__ be,
                                                  const float* __restrict__ rm, const float* __restrict__ rv,
                                                  uint2* __restrict__ Y,          // P2: 16 uint2 per row
                                                  int n) {
    __shared__ half2_t Wl2[16 * 64];            // 4 KB, k-pair-major
    __shared__ __align__(16) uint2 T2[32 * 8];  // 2 KB row tile (32 rows x 32 halves)
    __shared__ float Dl[32];
    int t = threadIdx.x;
    for (int idx = t; idx < 16 * 64; idx += 256) {
        int p = idx >> 6, j = idx & 63;
        half2_t w;
        w.x = (_Float16)W[(2 * p) * 64 + j];
        w.y = (_Float16)W[(2 * p + 1) * 64 + j];
        Wl2[idx] = w;
    }
    // Phase A: gather (lane = quarter-row of 4 halves)
    int lane = t & 7, nl = t >> 3;
    long i = (long)blockIdx.x * 32 + nl;
    float4 z = {0.f, 0.f, 0.f, 0.f};
    float4 o = z;
    float di = 0.f;
    if (i < n) {
        int k = base[i], kend = k + cnt[i];
        di = dinv[i];
        float4 a0 = z, a1 = z;
        for (; k + 1 < kend; k += 2) {
            int s0 = csr_s[k], s1 = csr_s[k + 1];
            float4 x0 = h4_to_f4(Xh[(long)s0 * 8 + lane]);
            float4 x1 = h4_to_f4(Xh[(long)s1 * 8 + lane]);
            a0.x += x0.x; a0.y += x0.y; a0.z += x0.z; a0.w += x0.w;
            a1.x += x1.x; a1.y += x1.y; a1.z += x1.z; a1.w += x1.w;
        }
        if (k < kend) {
            float4 xa = h4_to_f4(Xh[(long)csr_s[k] * 8 + lane]);
            a0.x += xa.x; a0.y += xa.y; a0.z += xa.z; a0.w += xa.w;
        }
        float4 xs = h4_to_f4(Xh[(long)i * 8 + lane]);
        o.x = di * (a0.x + a1.x + xs.x);
        o.y = di * (a0.y + a1.y + xs.y);
        o.z = di * (a0.z + a1.z + xs.z);
        o.w = di * (a0.w + a1.w + xs.w);
    }
    T2[nl * 8 + lane] = f4_to_h4(o);
    if (lane == 0) Dl[nl] = di;
    __syncthreads();

    // Phase B: GEMM. fl covers 4 fouts, rg covers TR=2 rows.
    int fl = t & 15, rg = t >> 4;
    int f0 = fl * 4;
    const uint4* T4 = reinterpret_cast<const uint4*>(T2);  // 4 uint4 per row
    float4 acc0 = z, acc1 = z;
    #pragma unroll
    for (int c = 0; c < 4; ++c) {
        uint4 ra = T4[(rg * 2 + 0) * 4 + c];
        uint4 rb = T4[(rg * 2 + 1) * 4 + c];
        #pragma unroll
        for (int q = 0; q < 4; ++q) {
            uint4 wv = *reinterpret_cast<const uint4*>(&Wl2[(c * 4 + q) * 64 + f0]);
            half2_t w0 = bch2(wv.x), w1 = bch2(wv.y), w2 = bch2(wv.z), w3 = bch2(wv.w);
            unsigned ua = (q == 0) ? ra.x : (q == 1) ? ra.y : (q == 2) ? ra.z : ra.w;
            unsigned ub = (q == 0) ? rb.x : (q == 1) ? rb.y : (q == 2) ? rb.z : rb.w;
            half2_t xa = bch2(ua), xb = bch2(ub);
            acc0.x = fdot2f(xa, w0, acc0.x); acc0.y = fdot2f(xa, w1, acc0.y);
            acc0.z = fdot2f(xa, w2, acc0.z); acc0.w = fdot2f(xa, w3, acc0.w);
            acc1.x = fdot2f(xb, w0, acc1.x); acc1.y = fdot2f(xb, w1, acc1.y);
            acc1.z = fdot2f(xb, w2, acc1.z); acc1.w = fdot2f(xb, w3, acc1.w);
        }
    }
    float4 bias = *reinterpret_cast<const float4*>(b + f0);
    float4 gg = *reinterpret_cast<const float4*>(g + f0);
    float4 ee = *reinterpret_cast<const float4*>(be + f0);
    float4 mm = *reinterpret_cast<const float4*>(rm + f0);
    float4 vv = *reinterpret_cast<const float4*>(rv + f0);
    float4 scale, shift;
    scale.x = gg.x * rsqrtf(vv.x + EPSF); shift.x = ee.x - mm.x * scale.x;
    scale.y = gg.y * rsqrtf(vv.y + EPSF); shift.y = ee.y - mm.y * scale.y;
    scale.z = gg.z * rsqrtf(vv.z + EPSF); shift.z = ee.z - mm.z * scale.z;
    scale.w = gg.w * rsqrtf(vv.w + EPSF); shift.w = ee.w - mm.w * scale.w;
    #pragma unroll
    for (int r = 0; r < 2; ++r) {
        long row = (long)blockIdx.x * 32 + rg * 2 + r;
        if (row >= n) continue;
        float4 v = r ? acc1 : acc0;
        float dv = Dl[rg * 2 + r];
        v.x = dv * elu_f((v.x + bias.x) * scale.x + shift.x);
        v.y = dv * elu_f((v.y + bias.y) * scale.y + shift.y);
        v.z = dv * elu_f((v.z + bias.z) * scale.z + shift.z);
        v.w = dv * elu_f((v.w + bias.w) * scale.w + shift.w);
        Y[row * 16 + fl] = f4_to_h4(v);
    }
}

// ---------------- fused gather + fp16 GEMM + W4-dot, layer 3 (64 -> 128 -> 1) ----------------
// Block = 32 rows. Phase A: gather fp16 P2 rows -> LDS tile. Phase B: dot2 GEMM x W3 +
// BN + ELU + dot(W4) + 32-lane reduce + dinv prescale -> y f32.
__global__ __launch_bounds__(256, 4) void k_fuse3(const int* __restrict__ base, const int* __restrict__ cnt,
                                                  const int* __restrict__ csr_s, const float* __restrict__ dinv,
                                                  const uint4* __restrict__ Xh,   // P2: 8 uint4 per row
                                                  const float* __restrict__ W, const float* __restrict__ b,
                                                  const float* __restrict__ g, const float* __restrict__ be,
                                                  const float* __restrict__ rm, const float* __restrict__ rv,
                                                  const float* __restrict__ W4,
                                                  float* __restrict__ y, int n) {
    __shared__ half2_t Wl2[32 * 128];           // 16 KB, k-pair-major
    __shared__ uint4 T3[32 * 8];                // 4 KB row tile (32 rows x 64 halves)
    __shared__ float Dl[32];
    int t = threadIdx.x;
    for (int idx = t; idx < 32 * 128; idx += 256) {
        int p = idx >> 7, j = idx & 127;
        half2_t w;
        w.x = (_Float16)W[(2 * p) * 128 + j];
        w.y = (_Float16)W[(2 * p + 1) * 128 + j];
        Wl2[idx] = w;
    }
    // Phase A: gather (lane = eighth-row of 8 halves = uint4)
    int lane = t & 7, nl = t >> 3;
    long i = (long)blockIdx.x * 32 + nl;
    float4 z = {0.f, 0.f, 0.f, 0.f};
    float4 oLo = z, oHi = z;
    float di = 0.f;
    if (i < n) {
        int k = base[i], kend = k + cnt[i];
        di = dinv[i];
        float4 aL0 = z, aH0 = z, aL1 = z, aH1 = z;
        for (; k + 1 < kend; k += 2) {
            int s0 = csr_s[k], s1 = csr_s[k + 1];
            uint4 u0 = Xh[(long)s0 * 8 + lane];
            uint4 u1 = Xh[(long)s1 * 8 + lane];
            float4 l0 = h4_to_f4(make_uint2(u0.x, u0.y)), h0 = h4_to_f4(make_uint2(u0.z, u0.w));
            float4 l1 = h4_to_f4(make_uint2(u1.x, u1.y)), h1 = h4_to_f4(make_uint2(u1.z, u1.w));
            aL0.x += l0.x; aL0.y += l0.y; aL0.z += l0.z; aL0.w += l0.w;
            aH0.x += h0.x; aH0.y += h0.y; aH0.z += h0.z; aH0.w += h0.w;
            aL1.x += l1.x; aL1.y += l1.y; aL1.z += l1.z; aL1.w += l1.w;
            aH1.x += h1.x; aH1.y += h1.y; aH1.z += h1.z; aH1.w += h1.w;
        }
        if (k < kend) {
            uint4 u0 = Xh[(long)csr_s[k] * 8 + lane];
            float4 l0 = h4_to_f4(make_uint2(u0.x, u0.y)), h0 = h4_to_f4(make_uint2(u0.z, u0.w));
            aL0.x += l0.x; aL0.y += l0.y; aL0.z += l0.z; aL0.w += l0.w;
            aH0.x += h0.x; aH0.y += h0.y; aH0.z += h0.z; aH0.w += h0.w;
        }
        uint4 us = Xh[(long)i * 8 + lane];
        float4 ls = h4_to_f4(make_uint2(us.x, us.y)), hs = h4_to_f4(make_uint2(us.z, us.w));
        oLo.x = di * (aL0.x + aL1.x + ls.x);
        oLo.y = di * (aL0.y + aL1.y + ls.y);
        oLo.z = di * (aL0.z + aL1.z + ls.z);
        oLo.w = di * (aL0.w + aL1.w + ls.w);
        oHi.x = di * (aH0.x + aH1.x + hs.x);
        oHi.y = di * (aH0.y + aH1.y + hs.y);
        oHi.z = di * (aH0.z + aH1.z + hs.z);
        oHi.w = di * (aH0.w + aH1.w + hs.w);
    }
    uint2 pl = f4_to_h4(oLo), ph = f4_to_h4(oHi);
    uint4 packed; packed.x = pl.x; packed.y = pl.y; packed.z = ph.x; packed.w = ph.y;
    T3[nl * 8 + lane] = packed;
    if (lane == 0) Dl[nl] = di;
    __syncthreads();

    // Phase B: GEMM. fl covers 4 fouts (of 128), rg covers TR=4 rows.
    int fl = t & 31, rg = t >> 5;
    int f0 = fl * 4;
    float4 acc[4] = {z, z, z, z};
    #pragma unroll 2
    for (int c = 0; c < 8; ++c) {
        uint4 rowc[4];
        #pragma unroll
        for (int r = 0; r < 4; ++r) rowc[r] = T3[(rg * 4 + r) * 8 + c];
        #pragma unroll
        for (int q = 0; q < 4; ++q) {
            uint4 wv = *reinterpret_cast<const uint4*>(&Wl2[(c * 4 + q) * 128 + f0]);
            half2_t w0 = bch2(wv.x), w1 = bch2(wv.y), w2 = bch2(wv.z), w3 = bch2(wv.w);
            #pragma unroll
            for (int r = 0; r < 4; ++r) {
                unsigned xu = (q == 0) ? rowc[r].x : (q == 1) ? rowc[r].y : (q == 2) ? rowc[r].z : rowc[r].w;
                half2_t xp = bch2(xu);
                acc[r].x = fdot2f(xp, w0, acc[r].x);
                acc[r].y = fdot2f(xp, w1, acc[r].y);
                acc[r].z = fdot2f(xp, w2, acc[r].z);
                acc[r].w = fdot2f(xp, w3, acc[r].w);
            }
        }
    }
    float4 bias = *reinterpret_cast<const float4*>(b + f0);
    float4 gg = *reinterpret_cast<const float4*>(g + f0);
    float4 ee = *reinterpret_cast<const float4*>(be + f0);
    float4 mm = *reinterpret_cast<const float4*>(rm + f0);
    float4 vv = *reinterpret_cast<const float4*>(rv + f0);
    float4 w4d = *reinterpret_cast<const float4*>(W4 + f0);
    float4 scale, shift;
    scale.x = gg.x * rsqrtf(vv.x + EPSF); shift.x = ee.x - mm.x * scale.x;
    scale.y = gg.y * rsqrtf(vv.y + EPSF); shift.y = ee.y - mm.y * scale.y;
    scale.z = gg.z * rsqrtf(vv.z + EPSF); shift.z = ee.z - mm.z * scale.z;
    scale.w = gg.w * rsqrtf(vv.w + EPSF); shift.w = ee.w - mm.w * scale.w;
    #pragma unroll
    for (int r = 0; r < 4; ++r) {
        long row = (long)blockIdx.x * 32 + rg * 4 + r;
        if (row >= n) continue;
        float4 v = acc[r];
        v.x = elu_f((v.x + bias.x) * scale.x + shift.x);
        v.y = elu_f((v.y + bias.y) * scale.y + shift.y);
        v.z = elu_f((v.z + bias.z) * scale.z + shift.z);
        v.w = elu_f((v.w + bias.w) * scale.w + shift.w);
        float p = v.x * w4d.x + v.y * w4d.y + v.z * w4d.z + v.w * w4d.w;
        #pragma unroll
        for (int m = 1; m < 32; m <<= 1) p += __shfl_xor(p, m, 64);
        if (fl == 0) y[row] = Dl[rg * 4 + r] * p;
    }
}

// ---------------- launch ----------------

extern "C" void kernel_launch(void* const* d_in, const int* in_sizes, int n_in,
                              void* d_out, int out_size, void* d_ws, size_t ws_size,
                              hipStream_t stream) {
    const float* x   = (const float*)d_in[0];
    const int*   edg = (const int*)d_in[1];
    const float* W1 = (const float*)d_in[2];
    const float* b1 = (const float*)d_in[3];
    const float* W2 = (const float*)d_in[4];
    const float* b2 = (const float*)d_in[5];
    const float* W3 = (const float*)d_in[6];
    const float* b3 = (const float*)d_in[7];
    const float* W4 = (const float*)d_in[8];
    const float* b4 = (const float*)d_in[9];
    const float* g1  = (const float*)d_in[10];
    const float* be1 = (const float*)d_in[11];
    const float* rm1 = (const float*)d_in[12];
    const float* rv1 = (const float*)d_in[13];
    const float* g2  = (const float*)d_in[14];
    const float* be2 = (const float*)d_in[15];
    const float* rm2 = (const float*)d_in[16];
    const float* rv2 = (const float*)d_in[17];
    const float* g3  = (const float*)d_in[18];
    const float* be3 = (const float*)d_in[19];
    const float* rm3 = (const float*)d_in[20];
    const float* rv3 = (const float*)d_in[21];
    float* out = (float*)d_out;

    const int N = in_sizes[0] / 64;
    const int E = in_sizes[1] / 2;
    const int* src = edg;
    const int* dst = edg + E;
    const int NB_BKT = (N + BKT_NODES - 1) / BKT_NODES;
    const int NTILES = (E + TILE_E - 1) / TILE_E;

    // workspace layout
    int*   bkt_cnt = (int*)d_ws;                    // 256
    int*   bbase   = bkt_cnt + 256;                 // 256
    int*   cursor  = bbase + 256;                   // 256
    int*   cnt     = cursor + 256;                  // N
    int*   base    = cnt + N;                       // N
    float* dinv    = (float*)(base + N);            // N
    int*   csr_s   = (int*)(dinv + N);              // E (permanent: gathers read it)
    float* featA   = (float*)(csr_s + E);           // N*64 f32 capacity
    float* featB   = featA + (size_t)N * 64;        // N*64 f32 capacity
    int2*  csr_tmp = (int2*)featA;                  // CSR-build-only alias

    auto nb = [](long total) { return (int)((total + 255) / 256); };

    // bucketed CSR build
    k_zero<<<1, 256, 0, stream>>>(bkt_cnt, 256);
    k_bhist<<<512, 256, 0, stream>>>(dst, bkt_cnt, E);
    k_bscan<<<1, 256, 0, stream>>>(bkt_cnt, bbase, cursor);
    k_bpart<<<NTILES, 256, 0, stream>>>(src, dst, cursor, csr_tmp, E);
    k_bfine<<<NB_BKT, 256, 0, stream>>>(csr_tmp, bbase, bkt_cnt, cnt, base, dinv, csr_s, N);

    // Layer 1 (64->32): f32 GEMM -> P1 fp16 (prescaled); gather+BN+ELU -> Q1 fp16 (prescaled)
    k_gemm_rt<64, 32, false, false, true, true><<<(N + 127) / 128, 256, 0, stream>>>(
        x, W1, nullptr, nullptr, nullptr, nullptr, nullptr, nullptr, dinv, featB, N);
    k_gather<32, true, true, true><<<(N + 31) / 32, 256, 0, stream>>>(base, cnt, csr_s, dinv, featB,
                                                                      b1, g1, be1, rm1, rv1, featA, N);

    // Layer 2 (32->64): fused gather(Q1) + GEMM + BN + ELU -> P2 fp16 (prescaled)
    k_fuse2<<<(N + 31) / 32, 256, 0, stream>>>(base, cnt, csr_s, dinv, (const uint2*)featA,
                                               W2, b2, g2, be2, rm2, rv2, (uint2*)featB, N);

    // Layer 3 (64->128->1): fused gather(P2) + GEMM + BN + ELU + dot(W4) (prescaled) -> y f32
    k_fuse3<<<(N + 31) / 32, 256, 0, stream>>>(base, cnt, csr_s, dinv, (const uint4*)featB,
                                               W3, b3, g3, be3, rm3, rv3, W4, featA, N);

    // Layer 4 (128->1): scalar gather + bias + sigmoid(elu(.)) -> d_out
    k_gather1_final<<<nb(N), 256, 0, stream>>>(base, cnt, csr_s, dinv, featA, b4, out, N);
}

// Round 13
// 339.304 us; speedup vs baseline: 1.5044x; 1.0135x over previous
//
#include <hip/hip_runtime.h>
#include <hip/hip_fp16.h>

#define EPSF 1e-5f
#define BKT_SHIFT 9
#define BKT_NODES 512              // nodes per bucket
#define TILE_E 4096                // edges per k_bpart block

typedef _Float16 half2_t __attribute__((ext_vector_type(2)));
typedef _Float16 half4_t __attribute__((ext_vector_type(4)));
typedef _Float16 half8_t __attribute__((ext_vector_type(8)));

__device__ __forceinline__ float elu_f(float x) { return x > 0.f ? x : expm1f(x); }

// v_dot2_f32_f16: 2 fp16 MACs, f32 accumulate
__device__ __forceinline__ float fdot2f(half2_t a, half2_t b, float c) {
#if __has_builtin(__builtin_amdgcn_fdot2)
    return __builtin_amdgcn_fdot2(a, b, c, false);
#else
    return c + (float)a.x * (float)b.x + (float)a.y * (float)b.y;
#endif
}
__device__ __forceinline__ half2_t bch2(unsigned u) { return __builtin_bit_cast(half2_t, u); }
__device__ __forceinline__ half4_t bch4(uint2 u) { return __builtin_bit_cast(half4_t, u); }
__device__ __forceinline__ half8_t bch8(uint4 u) { return __builtin_bit_cast(half8_t, u); }

__device__ __forceinline__ uint2 f4_to_h4(float4 v) {
    __half2 a = __floats2half2_rn(v.x, v.y);
    __half2 b = __floats2half2_rn(v.z, v.w);
    uint2 u;
    u.x = *reinterpret_cast<unsigned*>(&a);
    u.y = *reinterpret_cast<unsigned*>(&b);
    return u;
}

// ---------------- bucketed CSR build ----------------

__global__ __launch_bounds__(256) void k_zero(int* p, int n) {
    int i = blockIdx.x * 256 + threadIdx.x;
    if (i < n) p[i] = 0;
}

__global__ __launch_bounds__(256) void k_bhist(const int* __restrict__ dst, int* __restrict__ bkt_cnt, int E) {
    __shared__ int h[256];
    int t = threadIdx.x;
    h[t] = 0;
    __syncthreads();
    for (long e = (long)blockIdx.x * 256 + t; e < E; e += (long)gridDim.x * 256)
        atomicAdd(&h[dst[e] >> BKT_SHIFT], 1);
    __syncthreads();
    if (h[t]) atomicAdd(&bkt_cnt[t], h[t]);
}

__global__ __launch_bounds__(256) void k_bscan(const int* __restrict__ bkt_cnt, int* __restrict__ bbase,
                                               int* __restrict__ cursor) {
    __shared__ int sh[256];
    int t = threadIdx.x;
    int v = bkt_cnt[t];
    sh[t] = v;
    __syncthreads();
    for (int off = 1; off < 256; off <<= 1) {
        int add = (t >= off) ? sh[t - off] : 0;
        __syncthreads();
        sh[t] += add;
        __syncthreads();
    }
    int ex = sh[t] - v;
    bbase[t] = ex;
    cursor[t] = ex;
}

// partition edges into bucket-contiguous packed csr_tmp = (d&511)<<18 | src  (src < 2^17)
__global__ __launch_bounds__(256) void k_bpart(const int* __restrict__ src, const int* __restrict__ dst,
                                               int* __restrict__ cursor, unsigned* __restrict__ csr_tmp, int E) {
    __shared__ int hcnt[256];
    __shared__ int gbase[256];
    int t = threadIdx.x;
    long tile0 = (long)blockIdx.x * TILE_E;
    hcnt[t] = 0;
    __syncthreads();
    int d[16], s[16], rk[16];
    #pragma unroll
    for (int j = 0; j < 16; ++j) {
        long e = tile0 + j * 256 + t;
        if (e < E) {
            d[j] = dst[e];
            s[j] = src[e];
            rk[j] = atomicAdd(&hcnt[d[j] >> BKT_SHIFT], 1);
        }
    }
    __syncthreads();
    int c = hcnt[t];
    if (c) gbase[t] = atomicAdd(&cursor[t], c);
    __syncthreads();
    #pragma unroll
    for (int j = 0; j < 16; ++j) {
        long e = tile0 + j * 256 + t;
        if (e < E) {
            unsigned pk = ((unsigned)(d[j] & (BKT_NODES - 1)) << 18) | (unsigned)s[j];
            csr_tmp[gbase[d[j] >> BKT_SHIFT] + rk[j]] = pk;
        }
    }
}

__global__ __launch_bounds__(256) void k_bfine(const unsigned* __restrict__ csr_tmp, const int* __restrict__ bbase,
                                               const int* __restrict__ bkt_cnt, int* __restrict__ cnt,
                                               int* __restrict__ base, float* __restrict__ dinv,
                                               int* __restrict__ csr_s, int N) {
    __shared__ int cnt5[BKT_NODES];
    __shared__ int off5[BKT_NODES];
    __shared__ int sh[256];
    int b = blockIdx.x;
    int t = threadIdx.x;
    int d0 = b << BKT_SHIFT;
    int bb = bbase[b];
    int bc = bkt_cnt[b];
    cnt5[t] = 0;
    cnt5[t + 256] = 0;
    __syncthreads();
    for (int k = t; k < bc; k += 256) atomicAdd(&cnt5[csr_tmp[bb + k] >> 18], 1);
    __syncthreads();
    int v0 = cnt5[2 * t], v1 = cnt5[2 * t + 1];
    int p = v0 + v1;
    sh[t] = p;
    __syncthreads();
    for (int off = 1; off < 256; off <<= 1) {
        int add = (t >= off) ? sh[t - off] : 0;
        __syncthreads();
        sh[t] += add;
        __syncthreads();
    }
    int pre = sh[t] - p;
    off5[2 * t] = pre;
    off5[2 * t + 1] = pre + v0;
    #pragma unroll
    for (int j = 0; j < 2; ++j) {
        int idx = 2 * t + j;
        int i = d0 + idx;
        if (i < N) {
            int c = cnt5[idx];
            base[i] = bb + off5[idx];
            cnt[i] = c;
            dinv[i] = rsqrtf((float)(c + 1));  // +1 self-loop
        }
    }
    __syncthreads();
    for (int k = t; k < bc; k += 256) {
        unsigned e = csr_tmp[bb + k];
        int pos = bb + atomicAdd(&off5[e >> 18], 1);
        csr_s[pos] = (int)(e & 0x3FFFFu);
    }
}

// ---------------- layer-1 gather (fp16 in/out, half4 packed accumulation, BN+ELU+prescale) ----------------
__global__ __launch_bounds__(256) void k_gath1(const int* __restrict__ base, const int* __restrict__ cnt,
                                               const int* __restrict__ csr_s, const float* __restrict__ dinv,
                                               const uint2* __restrict__ Xh,   // P1: 8 uint2/row
                                               const float* __restrict__ b, const float* __restrict__ g,
                                               const float* __restrict__ be, const float* __restrict__ rm,
                                               const float* __restrict__ rv, uint2* __restrict__ out, int n) {
    int lane = threadIdx.x & 7, nl = threadIdx.x >> 3;
    long i = (long)blockIdx.x * 32 + nl;
    if (i >= n) return;
    int k = base[i], kend = k + cnt[i];
    float di = dinv[i];
    half4_t a0 = {0, 0, 0, 0}, a1 = a0, a2 = a0, a3 = a0;
    for (; k + 3 < kend; k += 4) {
        int s0 = csr_s[k], s1 = csr_s[k + 1], s2 = csr_s[k + 2], s3 = csr_s[k + 3];
        a0 += bch4(Xh[(long)s0 * 8 + lane]);
        a1 += bch4(Xh[(long)s1 * 8 + lane]);
        a2 += bch4(Xh[(long)s2 * 8 + lane]);
        a3 += bch4(Xh[(long)s3 * 8 + lane]);
    }
    for (; k < kend; ++k) a0 += bch4(Xh[(long)csr_s[k] * 8 + lane]);
    half4_t s4 = ((a0 + a1) + (a2 + a3)) + bch4(Xh[i * 8 + lane]);
    float4 o;
    o.x = di * (float)s4[0];
    o.y = di * (float)s4[1];
    o.z = di * (float)s4[2];
    o.w = di * (float)s4[3];
    float4 bb = reinterpret_cast<const float4*>(b)[lane];
    float4 gg = reinterpret_cast<const float4*>(g)[lane];
    float4 ee = reinterpret_cast<const float4*>(be)[lane];
    float4 mm = reinterpret_cast<const float4*>(rm)[lane];
    float4 vv = reinterpret_cast<const float4*>(rv)[lane];
    o.x = di * elu_f((o.x + bb.x - mm.x) * rsqrtf(vv.x + EPSF) * gg.x + ee.x);
    o.y = di * elu_f((o.y + bb.y - mm.y) * rsqrtf(vv.y + EPSF) * gg.y + ee.y);
    o.z = di * elu_f((o.z + bb.z - mm.z) * rsqrtf(vv.z + EPSF) * gg.z + ee.z);
    o.w = di * elu_f((o.w + bb.w - mm.w) * rsqrtf(vv.w + EPSF) * gg.w + ee.w);
    out[i * 8 + lane] = f4_to_h4(o);
}

// scalar gather for layer 4 (y pre-scaled by dinv) + bias + sigmoid(elu(.)) -> d_out
__global__ __launch_bounds__(256) void k_gather1_final(const int* __restrict__ base, const int* __restrict__ cnt,
                                                       const int* __restrict__ csr_s,
                                                       const float* __restrict__ dinv, const float* __restrict__ y,
                                                       const float* __restrict__ b4, float* __restrict__ out, int n) {
    int i = blockIdx.x * 256 + threadIdx.x;
    if (i >= n) return;
    int k = base[i];
    int kend = k + cnt[i];
    float di = dinv[i];
    float acc = 0.f;
    for (; k < kend; ++k) acc += y[csr_s[k]];
    float v = di * (acc + y[i]) + b4[0];
    v = elu_f(v);
    out[i] = 1.f / (1.f + expf(-v));
}

// ---------------- f32 register-tiled GEMM (layer 1: f32 x input -> fp16 prescaled) ----------------
template<int DIN, int DOUT>
__global__ __launch_bounds__(256, 4) void k_gemm1(const float* __restrict__ X, const float* __restrict__ W,
                                                  const float* __restrict__ dinv, uint2* __restrict__ Y, int n) {
    constexpr int TR = 4;
    constexpr int FL = DOUT / 4;
    constexpr int RG = 256 / FL;
    constexpr int BR = RG * TR;
    __shared__ float Wl[DIN * DOUT];
    for (int idx = threadIdx.x; idx < DIN * DOUT; idx += 256) Wl[idx] = W[idx];
    __syncthreads();
    const int fl = threadIdx.x % FL;
    const int rg = threadIdx.x / FL;
    const int f0 = fl * 4;
    const long r0 = (long)blockIdx.x * BR + (long)rg * TR;

    float4 z; z.x = z.y = z.z = z.w = 0.f;
    float4 acc[TR];
    #pragma unroll
    for (int r = 0; r < TR; ++r) acc[r] = z;

    #pragma unroll 2
    for (int k0 = 0; k0 < DIN; k0 += 4) {
        float4 xv[TR];
        #pragma unroll
        for (int r = 0; r < TR; ++r) {
            long row = r0 + r;
            xv[r] = (row < n) ? *reinterpret_cast<const float4*>(X + row * DIN + k0) : z;
        }
        #pragma unroll
        for (int kk = 0; kk < 4; ++kk) {
            float4 w4 = *reinterpret_cast<const float4*>(&Wl[(k0 + kk) * DOUT + f0]);
            #pragma unroll
            for (int r = 0; r < TR; ++r) {
                float xs = (kk == 0) ? xv[r].x : (kk == 1) ? xv[r].y : (kk == 2) ? xv[r].z : xv[r].w;
                acc[r].x += xs * w4.x;
                acc[r].y += xs * w4.y;
                acc[r].z += xs * w4.z;
                acc[r].w += xs * w4.w;
            }
        }
    }
    #pragma unroll
    for (int r = 0; r < TR; ++r) {
        long row = r0 + r;
        if (row >= n) continue;
        float dv = dinv[row];
        float4 v = acc[r];
        v.x *= dv; v.y *= dv; v.z *= dv; v.w *= dv;
        Y[row * FL + fl] = f4_to_h4(v);
    }
}

// ---------------- fused gather + fp16 GEMM, layer 2 (32 -> 64) ----------------
__global__ __launch_bounds__(256, 4) void k_fuse2(const int* __restrict__ base, const int* __restrict__ cnt,
                                                  const int* __restrict__ csr_s, const float* __restrict__ dinv,
                                                  const uint2* __restrict__ Xh,   // Q1: 8 uint2 per row
                                                  const float* __restrict__ W, const float* __restrict__ b,
                                                  const float* __restrict__ g, const float* __restrict__ be,
                                                  const float* __restrict__ rm, const float* __restrict__ rv,
                                                  uint2* __restrict__ Y,          // P2: 16 uint2 per row
                                                  int n) {
    __shared__ half2_t Wl2[16 * 64];            // 4 KB, k-pair-major
    __shared__ __align__(16) uint2 T2[32 * 8];  // 2 KB row tile (32 rows x 32 halves)
    __shared__ float Dl[32];
    int t = threadIdx.x;
    for (int idx = t; idx < 16 * 64; idx += 256) {
        int p = idx >> 6, j = idx & 63;
        half2_t w;
        w.x = (_Float16)W[(2 * p) * 64 + j];
        w.y = (_Float16)W[(2 * p + 1) * 64 + j];
        Wl2[idx] = w;
    }
    // Phase A: gather (half4 packed accumulation, 4-deep)
    int lane = t & 7, nl = t >> 3;
    long i = (long)blockIdx.x * 32 + nl;
    float4 z = {0.f, 0.f, 0.f, 0.f};
    float4 o = z;
    float di = 0.f;
    if (i < n) {
        int k = base[i], kend = k + cnt[i];
        di = dinv[i];
        half4_t a0 = {0, 0, 0, 0}, a1 = a0, a2 = a0, a3 = a0;
        for (; k + 3 < kend; k += 4) {
            int s0 = csr_s[k], s1 = csr_s[k + 1], s2 = csr_s[k + 2], s3 = csr_s[k + 3];
            a0 += bch4(Xh[(long)s0 * 8 + lane]);
            a1 += bch4(Xh[(long)s1 * 8 + lane]);
            a2 += bch4(Xh[(long)s2 * 8 + lane]);
            a3 += bch4(Xh[(long)s3 * 8 + lane]);
        }
        for (; k < kend; ++k) a0 += bch4(Xh[(long)csr_s[k] * 8 + lane]);
        half4_t s4 = ((a0 + a1) + (a2 + a3)) + bch4(Xh[i * 8 + lane]);
        o.x = di * (float)s4[0];
        o.y = di * (float)s4[1];
        o.z = di * (float)s4[2];
        o.w = di * (float)s4[3];
    }
    T2[nl * 8 + lane] = f4_to_h4(o);
    if (lane == 0) Dl[nl] = di;
    __syncthreads();

    // Phase B: GEMM. fl covers 4 fouts, rg covers TR=2 rows.
    int fl = t & 15, rg = t >> 4;
    int f0 = fl * 4;
    const uint4* T4 = reinterpret_cast<const uint4*>(T2);  // 4 uint4 per row
    float4 acc0 = z, acc1 = z;
    #pragma unroll
    for (int c = 0; c < 4; ++c) {
        uint4 ra = T4[(rg * 2 + 0) * 4 + c];
        uint4 rb = T4[(rg * 2 + 1) * 4 + c];
        #pragma unroll
        for (int q = 0; q < 4; ++q) {
            uint4 wv = *reinterpret_cast<const uint4*>(&Wl2[(c * 4 + q) * 64 + f0]);
            half2_t w0 = bch2(wv.x), w1 = bch2(wv.y), w2 = bch2(wv.z), w3 = bch2(wv.w);
            unsigned ua = (q == 0) ? ra.x : (q == 1) ? ra.y : (q == 2) ? ra.z : ra.w;
            unsigned ub = (q == 0) ? rb.x : (q == 1) ? rb.y : (q == 2) ? rb.z : rb.w;
            half2_t xa = bch2(ua), xb = bch2(ub);
            acc0.x = fdot2f(xa, w0, acc0.x); acc0.y = fdot2f(xa, w1, acc0.y);
            acc0.z = fdot2f(xa, w2, acc0.z); acc0.w = fdot2f(xa, w3, acc0.w);
            acc1.x = fdot2f(xb, w0, acc1.x); acc1.y = fdot2f(xb, w1, acc1.y);
            acc1.z = fdot2f(xb, w2, acc1.z); acc1.w = fdot2f(xb, w3, acc1.w);
        }
    }
    float4 bias = *reinterpret_cast<const float4*>(b + f0);
    float4 gg = *reinterpret_cast<const float4*>(g + f0);
    float4 ee = *reinterpret_cast<const float4*>(be + f0);
    float4 mm = *reinterpret_cast<const float4*>(rm + f0);
    float4 vv = *reinterpret_cast<const float4*>(rv + f0);
    float4 scale, shift;
    scale.x = gg.x * rsqrtf(vv.x + EPSF); shift.x = ee.x - mm.x * scale.x;
    scale.y = gg.y * rsqrtf(vv.y + EPSF); shift.y = ee.y - mm.y * scale.y;
    scale.z = gg.z * rsqrtf(vv.z + EPSF); shift.z = ee.z - mm.z * scale.z;
    scale.w = gg.w * rsqrtf(vv.w + EPSF); shift.w = ee.w - mm.w * scale.w;
    #pragma unroll
    for (int r = 0; r < 2; ++r) {
        long row = (long)blockIdx.x * 32 + rg * 2 + r;
        if (row >= n) continue;
        float4 v = r ? acc1 : acc0;
        float dv = Dl[rg * 2 + r];
        v.x = dv * elu_f((v.x + bias.x) * scale.x + shift.x);
        v.y = dv * elu_f((v.y + bias.y) * scale.y + shift.y);
        v.z = dv * elu_f((v.z + bias.z) * scale.z + shift.z);
        v.w = dv * elu_f((v.w + bias.w) * scale.w + shift.w);
        Y[row * 16 + fl] = f4_to_h4(v);
    }
}

// ---------------- fused gather + fp16 GEMM + W4-dot, layer 3 (64 -> 128 -> 1) ----------------
__global__ __launch_bounds__(256, 4) void k_fuse3(const int* __restrict__ base, const int* __restrict__ cnt,
                                                  const int* __restrict__ csr_s, const float* __restrict__ dinv,
                                                  const uint4* __restrict__ Xh,   // P2: 8 uint4 per row
                                                  const float* __restrict__ W, const float* __restrict__ b,
                                                  const float* __restrict__ g, const float* __restrict__ be,
                                                  const float* __restrict__ rm, const float* __restrict__ rv,
                                                  const float* __restrict__ W4,
                                                  float* __restrict__ y, int n) {
    __shared__ half2_t Wl2[32 * 128];           // 16 KB, k-pair-major
    __shared__ uint4 T3[32 * 8];                // 4 KB row tile (32 rows x 64 halves)
    __shared__ float Dl[32];
    int t = threadIdx.x;
    for (int idx = t; idx < 32 * 128; idx += 256) {
        int p = idx >> 7, j = idx & 127;
        half2_t w;
        w.x = (_Float16)W[(2 * p) * 128 + j];
        w.y = (_Float16)W[(2 * p + 1) * 128 + j];
        Wl2[idx] = w;
    }
    // Phase A: gather (half8 packed accumulation, 4-deep)
    int lane = t & 7, nl = t >> 3;
    long i = (long)blockIdx.x * 32 + nl;
    float4 z = {0.f, 0.f, 0.f, 0.f};
    float4 oLo = z, oHi = z;
    float di = 0.f;
    if (i < n) {
        int k = base[i], kend = k + cnt[i];
        di = dinv[i];
        half8_t a0 = {0, 0, 0, 0, 0, 0, 0, 0}, a1 = a0, a2 = a0, a3 = a0;
        for (; k + 3 < kend; k += 4) {
            int s0 = csr_s[k], s1 = csr_s[k + 1], s2 = csr_s[k + 2], s3 = csr_s[k + 3];
            a0 += bch8(Xh[(long)s0 * 8 + lane]);
            a1 += bch8(Xh[(long)s1 * 8 + lane]);
            a2 += bch8(Xh[(long)s2 * 8 + lane]);
            a3 += bch8(Xh[(long)s3 * 8 + lane]);
        }
        for (; k < kend; ++k) a0 += bch8(Xh[(long)csr_s[k] * 8 + lane]);
        half8_t s8 = ((a0 + a1) + (a2 + a3)) + bch8(Xh[i * 8 + lane]);
        oLo.x = di * (float)s8[0]; oLo.y = di * (float)s8[1];
        oLo.z = di * (float)s8[2]; oLo.w = di * (float)s8[3];
        oHi.x = di * (float)s8[4]; oHi.y = di * (float)s8[5];
        oHi.z = di * (float)s8[6]; oHi.w = di * (float)s8[7];
    }
    uint2 pl = f4_to_h4(oLo), ph = f4_to_h4(oHi);
    uint4 packed; packed.x = pl.x; packed.y = pl.y; packed.z = ph.x; packed.w = ph.y;
    T3[nl * 8 + lane] = packed;
    if (lane == 0) Dl[nl] = di;
    __syncthreads();

    // Phase B: GEMM. fl covers 4 fouts (of 128), rg covers TR=4 rows.
    int fl = t & 31, rg = t >> 5;
    int f0 = fl * 4;
    float4 acc[4] = {z, z, z, z};
    #pragma unroll 2
    for (int c = 0; c < 8; ++c) {
        uint4 rowc[4];
        #pragma unroll
        for (int r = 0; r < 4; ++r) rowc[r] = T3[(rg * 4 + r) * 8 + c];
        #pragma unroll
        for (int q = 0; q < 4; ++q) {
            uint4 wv = *reinterpret_cast<const uint4*>(&Wl2[(c * 4 + q) * 128 + f0]);
            half2_t w0 = bch2(wv.x), w1 = bch2(wv.y), w2 = bch2(wv.z), w3 = bch2(wv.w);
            #pragma unroll
            for (int r = 0; r < 4; ++r) {
                unsigned xu = (q == 0) ? rowc[r].x : (q == 1) ? rowc[r].y : (q == 2) ? rowc[r].z : rowc[r].w;
                half2_t xp = bch2(xu);
                acc[r].x = fdot2f(xp, w0, acc[r].x);
                acc[r].y = fdot2f(xp, w1, acc[r].y);
                acc[r].z = fdot2f(xp, w2, acc[r].z);
                acc[r].w = fdot2f(xp, w3, acc[r].w);
            }
        }
    }
    float4 bias = *reinterpret_cast<const float4*>(b + f0);
    float4 gg = *reinterpret_cast<const float4*>(g + f0);
    float4 ee = *reinterpret_cast<const float4*>(be + f0);
    float4 mm = *reinterpret_cast<const float4*>(rm + f0);
    float4 vv = *reinterpret_cast<const float4*>(rv + f0);
    float4 w4d = *reinterpret_cast<const float4*>(W4 + f0);
    float4 scale, shift;
    scale.x = gg.x * rsqrtf(vv.x + EPSF); shift.x = ee.x - mm.x * scale.x;
    scale.y = gg.y * rsqrtf(vv.y + EPSF); shift.y = ee.y - mm.y * scale.y;
    scale.z = gg.z * rsqrtf(vv.z + EPSF); shift.z = ee.z - mm.z * scale.z;
    scale.w = gg.w * rsqrtf(vv.w + EPSF); shift.w = ee.w - mm.w * scale.w;
    #pragma unroll
    for (int r = 0; r < 4; ++r) {
        long row = (long)blockIdx.x * 32 + rg * 4 + r;
        if (row >= n) continue;
        float4 v = acc[r];
        v.x = elu_f((v.x + bias.x) * scale.x + shift.x);
        v.y = elu_f((v.y + bias.y) * scale.y + shift.y);
        v.z = elu_f((v.z + bias.z) * scale.z + shift.z);
        v.w = elu_f((v.w + bias.w) * scale.w + shift.w);
        float p = v.x * w4d.x + v.y * w4d.y + v.z * w4d.z + v.w * w4d.w;
        #pragma unroll
        for (int m = 1; m < 32; m <<= 1) p += __shfl_xor(p, m, 64);
        if (fl == 0) y[row] = Dl[rg * 4 + r] * p;
    }
}

// ---------------- launch ----------------

extern "C" void kernel_launch(void* const* d_in, const int* in_sizes, int n_in,
                              void* d_out, int out_size, void* d_ws, size_t ws_size,
                              hipStream_t stream) {
    const float* x   = (const float*)d_in[0];
    const int*   edg = (const int*)d_in[1];
    const float* W1 = (const float*)d_in[2];
    const float* b1 = (const float*)d_in[3];
    const float* W2 = (const float*)d_in[4];
    const float* b2 = (const float*)d_in[5];
    const float* W3 = (const float*)d_in[6];
    const float* b3 = (const float*)d_in[7];
    const float* W4 = (const float*)d_in[8];
    const float* b4 = (const float*)d_in[9];
    const float* g1  = (const float*)d_in[10];
    const float* be1 = (const float*)d_in[11];
    const float* rm1 = (const float*)d_in[12];
    const float* rv1 = (const float*)d_in[13];
    const float* g2  = (const float*)d_in[14];
    const float* be2 = (const float*)d_in[15];
    const float* rm2 = (const float*)d_in[16];
    const float* rv2 = (const float*)d_in[17];
    const float* g3  = (const float*)d_in[18];
    const float* be3 = (const float*)d_in[19];
    const float* rm3 = (const float*)d_in[20];
    const float* rv3 = (const float*)d_in[21];
    float* out = (float*)d_out;

    const int N = in_sizes[0] / 64;
    const int E = in_sizes[1] / 2;
    const int* src = edg;
    const int* dst = edg + E;
    const int NB_BKT = (N + BKT_NODES - 1) / BKT_NODES;
    const int NTILES = (E + TILE_E - 1) / TILE_E;

    // workspace layout
    int*      bkt_cnt = (int*)d_ws;                 // 256
    int*      bbase   = bkt_cnt + 256;              // 256
    int*      cursor  = bbase + 256;                // 256
    int*      cnt     = cursor + 256;               // N
    int*      base    = cnt + N;                    // N
    float*    dinv    = (float*)(base + N);         // N
    int*      csr_s   = (int*)(dinv + N);           // E (permanent: gathers read it)
    float*    featA   = (float*)(csr_s + E);        // N*64 f32 capacity
    float*    featB   = featA + (size_t)N * 64;     // N*64 f32 capacity
    unsigned* csr_tmp = (unsigned*)featA;           // CSR-build-only alias (E uints)

    auto nb = [](long total) { return (int)((total + 255) / 256); };

    // bucketed CSR build
    k_zero<<<1, 256, 0, stream>>>(bkt_cnt, 256);
    k_bhist<<<512, 256, 0, stream>>>(dst, bkt_cnt, E);
    k_bscan<<<1, 256, 0, stream>>>(bkt_cnt, bbase, cursor);
    k_bpart<<<NTILES, 256, 0, stream>>>(src, dst, cursor, csr_tmp, E);
    k_bfine<<<NB_BKT, 256, 0, stream>>>(csr_tmp, bbase, bkt_cnt, cnt, base, dinv, csr_s, N);

    // Layer 1 (64->32): f32 GEMM -> P1 fp16 (prescaled); gather+BN+ELU -> Q1 fp16 (prescaled)
    k_gemm1<64, 32><<<(N + 127) / 128, 256, 0, stream>>>(x, W1, dinv, (uint2*)featB, N);
    k_gath1<<<(N + 31) / 32, 256, 0, stream>>>(base, cnt, csr_s, dinv, (const uint2*)featB,
                                               b1, g1, be1, rm1, rv1, (uint2*)featA, N);

    // Layer 2 (32->64): fused gather(Q1) + GEMM + BN + ELU -> P2 fp16 (prescaled)
    k_fuse2<<<(N + 31) / 32, 256, 0, stream>>>(base, cnt, csr_s, dinv, (const uint2*)featA,
                                               W2, b2, g2, be2, rm2, rv2, (uint2*)featB, N);

    // Layer 3 (64->128->1): fused gather(P2) + GEMM + BN + ELU + dot(W4) (prescaled) -> y f32
    k_fuse3<<<(N + 31) / 32, 256, 0, stream>>>(base, cnt, csr_s, dinv, (const uint4*)featB,
                                               W3, b3, g3, be3, rm3, rv3, W4, featA, N);

    // Layer 4 (128->1): scalar gather + bias + sigmoid(elu(.)) -> d_out
    k_gather1_final<<<nb(N), 256, 0, stream>>>(base, cnt, csr_s, dinv, featA, b4, out, N);
}